// Round 11
// baseline (818.994 us; speedup 1.0000x reference)
//
#include <hip/hip_runtime.h>
#include <hip/hip_bf16.h>
#include <math.h>

typedef __hip_bfloat16 bf16;
typedef __attribute__((ext_vector_type(8))) short short8;
typedef __attribute__((ext_vector_type(8))) unsigned short u16x8;
typedef __attribute__((ext_vector_type(4))) float f32x4;
typedef long long ll;

#define B_ 8
#define HEADS_ 4
#define KV_ 960
#define HW_ 1024
#define CKV_ 3840   // KV_*HEADS_

// ---------------------------------------------------------------------------
// helpers
// ---------------------------------------------------------------------------
__device__ __forceinline__ float wredsum(float v) {
#pragma unroll
  for (int o = 32; o > 0; o >>= 1) v += __shfl_xor(v, o);
  return v;
}
__device__ __forceinline__ float wredmax(float v) {
#pragma unroll
  for (int o = 32; o > 0; o >>= 1) v = fmaxf(v, __shfl_xor(v, o));
  return v;
}

__device__ __forceinline__ float bfu2f(unsigned short u) {
  union { unsigned int i; float f; } c;
  c.i = ((unsigned int)u) << 16;
  return c.f;
}
__device__ __forceinline__ unsigned short f2bfu(float f) {
  bf16 h = __float2bfloat16(f);
  return *(unsigned short*)&h;
}

__device__ __forceinline__ void gl_lds16(const void* g, void* l) {
  __builtin_amdgcn_global_load_lds(
      (const __attribute__((address_space(1))) unsigned*)g,
      (__attribute__((address_space(3))) unsigned*)l, 16, 0, 0);
}

// ---------------------------------------------------------------------------
// K0a: elementwise f32 -> bf16 cast (weights). n % 4 == 0.
// ---------------------------------------------------------------------------
__global__ void __launch_bounds__(256) castw(const float* __restrict__ in,
                                             bf16* __restrict__ out, int n) {
  int i = (blockIdx.x * 256 + threadIdx.x) * 4;
  if (i < n) {
    float4 v = *(const float4*)(in + i);
    out[i] = __float2bfloat16(v.x);
    out[i + 1] = __float2bfloat16(v.y);
    out[i + 2] = __float2bfloat16(v.z);
    out[i + 3] = __float2bfloat16(v.w);
  }
}

// ---------------------------------------------------------------------------
// K0b: transpose+cast: in [z][R][1024] f32 -> out [z][1024][R] bf16.
// ---------------------------------------------------------------------------
template <typename InT>
__global__ void __launch_bounds__(256) tcast(const InT* __restrict__ in,
                                             bf16* __restrict__ out, int R,
                                             ll inZ, ll outZ) {
  __shared__ float t[32][33];
  const int x = threadIdx.x & 31, y0 = threadIdx.x >> 5;
  const int c0 = blockIdx.x << 5, r0 = blockIdx.y << 5;
  const InT* ip = in + (ll)blockIdx.z * inZ + (ll)r0 * 1024 + c0;
  bf16* op = out + (ll)blockIdx.z * outZ + (ll)c0 * R + r0;
#pragma unroll
  for (int i = 0; i < 4; i++) {
    int r = y0 + i * 8;
    float v;
    if constexpr (__is_same(InT, float)) v = ip[(ll)r * 1024 + x];
    else v = __bfloat162float(ip[(ll)r * 1024 + x]);
    t[r][x] = v;
  }
  __syncthreads();
#pragma unroll
  for (int i = 0; i < 4; i++) {
    int cc = y0 + i * 8;
    op[(ll)cc * R + x] = __float2bfloat16(t[x][cc]);
  }
}

// ---------------------------------------------------------------------------
// gemm_mfma: 128x128 / BK=32 / 2-phase dbuf (proven).
// ---------------------------------------------------------------------------
template <int OUTMODE, bool STATS>
__global__ void __launch_bounds__(256) gemm_mfma(
    const bf16* __restrict__ A, const bf16* __restrict__ Bt, void* __restrict__ Y,
    int M, int N, int K, int nh,
    ll aZ, ll aH, ll bZ, ll bH, ll yZ, int ldy, float scale,
    float* __restrict__ part) {
  __shared__ bf16 As[2][128 * 32];
  __shared__ bf16 Bs[2][128 * 32];
  __shared__ float rs1[4], rs2[4];
  const int tid = threadIdx.x;
  const int lane = tid & 63;
  const int wave = tid >> 6;
  const int wr = wave >> 1, wc = wave & 1;

  const int gy = gridDim.y, gz = gridDim.z;
  int orig = (blockIdx.z * gy + blockIdx.y) * 8 + blockIdx.x;
  int cpx = (gy * gz);
  int flat = (orig & 7) * cpx + (orig >> 3);
  const int lx = flat & 7;
  int rest = flat >> 3;
  const int ly = rest % gy;
  const int lz = rest / gy;

  const int z = lz;
  const int m0 = ly << 7, n0 = lx << 7;

  f32x4 acc[4][4];
#pragma unroll
  for (int i = 0; i < 4; i++)
#pragma unroll
    for (int j = 0; j < 4; j++) acc[i][j] = (f32x4){0.f, 0.f, 0.f, 0.f};

  const int frow = lane & 15;
  const int kq = lane >> 4;

  const bf16* Ah = A + (ll)z * aZ;
  const bf16* Bh = Bt + (ll)z * bZ;
  int k0n = 0;

  auto stage = [&](int buf) {
#pragma unroll
    for (int t = 0; t < 2; t++) {
      const int e = (wave * 2 + t) * 64 + lane;
      const int row = e >> 2;
      const int ks = (e & 3) ^ ((row >> 1) & 3);
      int gr = m0 + row; gr = gr < M ? gr : M - 1;
      gl_lds16(Ah + (ll)gr * K + k0n + ks * 8,
               (char*)&As[buf][0] + (wave * 2 + t) * 1024);
      int rn = n0 + row; rn = rn < N ? rn : N - 1;
      gl_lds16(Bh + (ll)rn * K + k0n + ks * 8,
               (char*)&Bs[buf][0] + (wave * 2 + t) * 1024);
    }
  };

  const int kpt = K >> 5;
  const int iters = nh * kpt;
  stage(0);
  __syncthreads();

  int buf = 0;
  for (int it = 0; it < iters; ++it) {
    if (it + 1 < iters) {
      k0n += 32;
      if (k0n == K) { k0n = 0; Ah += aH; Bh += bH; }
      stage(buf ^ 1);
    }
    short8 af[4], bfr[4];
#pragma unroll
    for (int fm = 0; fm < 4; fm++) {
      const int row = wr * 64 + fm * 16 + frow;
      af[fm] = *(const short8*)&As[buf][((row << 2) | (kq ^ ((row >> 1) & 3))) << 3];
    }
#pragma unroll
    for (int fn = 0; fn < 4; fn++) {
      const int row = wc * 64 + fn * 16 + frow;
      bfr[fn] = *(const short8*)&Bs[buf][((row << 2) | (kq ^ ((row >> 1) & 3))) << 3];
    }
#pragma unroll
    for (int fm = 0; fm < 4; fm++)
#pragma unroll
      for (int fn = 0; fn < 4; fn++)
        acc[fm][fn] = __builtin_amdgcn_mfma_f32_16x16x32_bf16(
            af[fm], bfr[fn], acc[fm][fn], 0, 0, 0);
    __syncthreads();
    buf ^= 1;
  }

  const int rq = kq << 2;
  float lsum = 0.f, lsq = 0.f;
#pragma unroll
  for (int fm = 0; fm < 4; fm++) {
    const int mrow = m0 + wr * 64 + fm * 16 + rq;
#pragma unroll
    for (int fn = 0; fn < 4; fn++) {
      const int ncol = n0 + wc * 64 + fn * 16 + frow;
      if (ncol >= N) continue;
      if constexpr (OUTMODE == 0) {
        float* Yp = (float*)Y + (ll)z * yZ;
#pragma unroll
        for (int i = 0; i < 4; i++)
          if (mrow + i < M) {
            float v = acc[fm][fn][i] * scale;
            Yp[(ll)(mrow + i) * ldy + ncol] = v;
            if constexpr (STATS) { lsum += v; lsq += v * v; }
          }
      } else if constexpr (OUTMODE == 1) {
        bf16* Yp = (bf16*)Y + (ll)z * yZ;
#pragma unroll
        for (int i = 0; i < 4; i++)
          if (mrow + i < M)
            Yp[(ll)(mrow + i) * ldy + ncol] =
                __float2bfloat16(acc[fm][fn][i] * scale);
      } else {
        if (mrow < M) {
          bf16* Yp = (bf16*)Y + (ll)z * yZ + (ll)ncol * ldy + mrow;
#pragma unroll
          for (int i = 0; i < 4; i++)
            Yp[i] = __float2bfloat16(acc[fm][fn][i] * scale);
        }
      }
    }
  }
  if constexpr (STATS) {
    lsum = wredsum(lsum);
    lsq = wredsum(lsq);
    if (lane == 0) { rs1[wave] = lsum; rs2[wave] = lsq; }
    __syncthreads();
    if (tid == 0) {
      int slot = ly * 8 + lx;
      part[((ll)z * 32 + slot) * 2] = rs1[0] + rs1[1] + rs1[2] + rs1[3];
      part[((ll)z * 32 + slot) * 2 + 1] = rs2[0] + rs2[1] + rs2[2] + rs2[3];
    }
  }
}

// ---------------------------------------------------------------------------
// gemm8: 256x256, BK=64, 512 thr, dbuf, k-phase schedule (R11):
// LDS = [2 buf][2 kh][256 rows][32 k] per matrix (quarter = 16KB).
// Each phase consumes ONE k-half -> late-binding quarters -> vmcnt(4) at
// EVERY phase entry (incl. after prologue; vmcnt(0) only at very last phase).
// Per phase: 12 ds_read_b128, 4 prefetch loads, 32 MFMA, 1 barrier.
// Read swizzle kc = kq ^ ((frow>>1)&3) (8 bankpos x 2 lanes = conflict-free);
// staging source pre-applies the same involution (LDS dest linear).
// ---------------------------------------------------------------------------
template <int OUTMODE, bool STATS>
__global__ void __launch_bounds__(512, 2) gemm8(
    const bf16* __restrict__ A, const bf16* __restrict__ Bt, void* __restrict__ Y,
    int M, int N, int K, int nh,
    ll aZ, ll aH, ll bZ, ll bH, ll yZ, int ldy, float scale,
    float* __restrict__ part) {
  __shared__ char lds[131072];           // A: [0,64K) ; B: [64K,128K)
  __shared__ float rs1[8], rs2[8];
  const int tid = threadIdx.x;
  const int lane = tid & 63;
  const int wave = tid >> 6;
  const int wm = wave >> 2, wn = wave & 3;

  const int nx = gridDim.x, my = gridDim.y;
  const int nwg = nx * my * gridDim.z;
  int orig = (blockIdx.z * my + blockIdx.y) * nx + blockIdx.x;
  int q8 = nwg >> 3, r8 = nwg & 7;
  int xcd = orig & 7, bidx = orig >> 3;
  int flat = (xcd < r8) ? xcd * (q8 + 1) + bidx
                        : r8 * (q8 + 1) + (xcd - r8) * q8 + bidx;
  const int lx = flat % nx;
  int rest = flat / nx;
  const int ly = rest % my;
  const int lz = rest / my;

  const int m0 = ly << 8, n0 = lx << 8;
  const int ktiles = K >> 6;
  const int nt = nh * ktiles;

  f32x4 acc[8][4];
#pragma unroll
  for (int i = 0; i < 8; i++)
#pragma unroll
    for (int j = 0; j < 4; j++) acc[i][j] = (f32x4){0.f, 0.f, 0.f, 0.f};

  const int frow = lane & 15;
  const int kq = lane >> 4;
  const int rswz = (frow >> 1) & 3;

  // stage one quarter (matrix half-K): 256 rows x 32 k, 2 loads/thread.
  // slot s = r*512+tid -> (row=s>>2, phys chunk p=s&3) holds global chunk
  // p ^ ((row>>1)&3); LDS dest linear (base + r*8192 + tid*16).
  auto stageQ = [&](int matB, int kh, int tt, int buf) {
    int h = tt / ktiles;
    int koff = ((tt % ktiles) << 6) + (kh << 5);
#pragma unroll
    for (int r = 0; r < 2; r++) {
      int s = (r << 9) + tid;
      int row = s >> 2;
      int kc = (s & 3) ^ ((row >> 1) & 3);
      if (!matB) {
        int gr = m0 + row; gr = gr < M ? gr : M - 1;
        gl_lds16(A + (ll)lz * aZ + (ll)h * aH + (ll)gr * K + koff + (kc << 3),
                 lds + buf * 32768 + (kh << 14) + (r << 13) + (tid << 4));
      } else {
        int gr = n0 + row; gr = gr < N ? gr : N - 1;
        gl_lds16(Bt + (ll)lz * bZ + (ll)h * bH + (ll)gr * K + koff + (kc << 3),
                 lds + 65536 + buf * 32768 + (kh << 14) + (r << 13) + (tid << 4));
      }
    }
  };

  auto readA = [&](int fm, int kh, int buf) -> short8 {
    int row = wm * 128 + fm * 16 + frow;
    int kc = kq ^ rswz;
    return *(const short8*)(lds + buf * 32768 + (kh << 14) + row * 64 + (kc << 4));
  };
  auto readB = [&](int fn, int kh, int buf) -> short8 {
    int row = wn * 64 + fn * 16 + frow;
    int kc = kq ^ rswz;
    return *(const short8*)(lds + 65536 + buf * 32768 + (kh << 14) + row * 64 + (kc << 4));
  };

  // prologue: tile 0 fully staged in steady-state order (Ak0,Bk0,Ak1,Bk1).
  stageQ(0, 0, 0, 0); stageQ(1, 0, 0, 0);
  stageQ(0, 1, 0, 0); stageQ(1, 1, 0, 0);

  for (int tt = 0; tt < nt; ++tt) {
    const int buf = tt & 1;
    const bool hasNext = (tt + 1 < nt);
#pragma unroll
    for (int kh = 0; kh < 2; kh++) {
      if (hasNext || kh == 0) asm volatile("s_waitcnt vmcnt(4)" ::: "memory");
      else                    asm volatile("s_waitcnt vmcnt(0)" ::: "memory");
      __builtin_amdgcn_s_barrier();
      __builtin_amdgcn_sched_barrier(0);
      short8 af[8], bf4[4];
#pragma unroll
      for (int fm = 0; fm < 8; fm++) af[fm] = readA(fm, kh, buf);
#pragma unroll
      for (int fn = 0; fn < 4; fn++) bf4[fn] = readB(fn, kh, buf);
      if (hasNext) { stageQ(0, kh, tt + 1, buf ^ 1); stageQ(1, kh, tt + 1, buf ^ 1); }
      __builtin_amdgcn_s_setprio(1);
#pragma unroll
      for (int fm = 0; fm < 8; fm++)
#pragma unroll
        for (int fn = 0; fn < 4; fn++)
          acc[fm][fn] = __builtin_amdgcn_mfma_f32_16x16x32_bf16(
              af[fm], bf4[fn], acc[fm][fn], 0, 0, 0);
      __builtin_amdgcn_s_setprio(0);
    }
  }

  const int rq = kq << 2;
  float lsum = 0.f, lsq = 0.f;
#pragma unroll
  for (int fm = 0; fm < 8; fm++) {
    const int mrow = m0 + wm * 128 + fm * 16 + rq;
#pragma unroll
    for (int fn = 0; fn < 4; fn++) {
      const int ncol = n0 + wn * 64 + fn * 16 + frow;
      if (ncol >= N) continue;
      if constexpr (OUTMODE == 0) {
        float* Yp = (float*)Y + (ll)lz * yZ;
#pragma unroll
        for (int i = 0; i < 4; i++)
          if (mrow + i < M) {
            float v = acc[fm][fn][i] * scale;
            Yp[(ll)(mrow + i) * ldy + ncol] = v;
            if constexpr (STATS) { lsum += v; lsq += v * v; }
          }
      } else if constexpr (OUTMODE == 1) {
        bf16* Yp = (bf16*)Y + (ll)lz * yZ;
#pragma unroll
        for (int i = 0; i < 4; i++)
          if (mrow + i < M)
            Yp[(ll)(mrow + i) * ldy + ncol] =
                __float2bfloat16(acc[fm][fn][i] * scale);
      } else {
        if (mrow < M) {
          bf16* Yp = (bf16*)Y + (ll)lz * yZ + (ll)ncol * ldy + mrow;
#pragma unroll
          for (int i = 0; i < 4; i++)
            Yp[i] = __float2bfloat16(acc[fm][fn][i] * scale);
        }
      }
    }
  }
  if constexpr (STATS) {
    lsum = wredsum(lsum);
    lsq = wredsum(lsq);
    if (lane == 0) { rs1[wave] = lsum; rs2[wave] = lsq; }
    __syncthreads();
    if (tid == 0) {
      float s = 0.f, s2 = 0.f;
#pragma unroll
      for (int w = 0; w < 8; w++) { s += rs1[w]; s2 += rs2[w]; }
      int slot = ly * nx + lx;
      part[((ll)lz * 32 + slot) * 2] = s;
      part[((ll)lz * 32 + slot) * 2 + 1] = s2;
    }
  }
}

// ---------------------------------------------------------------------------
// pv_reduce: OtT[b][off] = 0.25 * sum_{s<4} part[(b*4+s)][off]  (bf16)
// ---------------------------------------------------------------------------
__global__ void __launch_bounds__(256) pv_reduce(const bf16* __restrict__ part,
                                                 bf16* __restrict__ out,
                                                 int planeShift) {
  const ll idx = ((ll)blockIdx.x * 256 + threadIdx.x) * 4;
  const int b = (int)(idx >> planeShift);
  const ll off = idx - ((ll)b << planeShift);
  const bf16* base = part + (((ll)b * 4) << planeShift) + off;
  float a0 = 0.f, a1 = 0.f, a2 = 0.f, a3 = 0.f;
#pragma unroll
  for (int s = 0; s < 4; s++) {
    ushort4 u = *(const ushort4*)(base + ((ll)s << planeShift));
    a0 += bfu2f(u.x); a1 += bfu2f(u.y); a2 += bfu2f(u.z); a3 += bfu2f(u.w);
  }
  ushort4 o;
  o.x = f2bfu(a0 * 0.25f);
  o.y = f2bfu(a1 * 0.25f);
  o.z = f2bfu(a2 * 0.25f);
  o.w = f2bfu(a3 * 0.25f);
  *(ushort4*)(out + idx) = o;
}

// ---------------------------------------------------------------------------
// K2: depthwise 3x3 (pad 1), optional fused l2norm. 256 thr, 4 px/thread.
// ---------------------------------------------------------------------------
template <bool NORM>
__global__ void __launch_bounds__(256) dw3x3v(const bf16* __restrict__ in,
                                              const float* __restrict__ w9,
                                              bf16* __restrict__ out, int C) {
  __shared__ float tile[34][36];
  __shared__ float red[4];
  const int bc = blockIdx.x;
  const int ch = bc % C;
  const int tid = threadIdx.x;
  const int y = tid >> 3;
  const int x0 = (tid & 7) << 2;
  const bf16* ip = in + ((size_t)bc << 10);

  ushort4 u = *(const ushort4*)(ip + (y << 5) + x0);
  tile[y + 1][x0 + 1] = bfu2f(u.x);
  tile[y + 1][x0 + 2] = bfu2f(u.y);
  tile[y + 1][x0 + 3] = bfu2f(u.z);
  tile[y + 1][x0 + 4] = bfu2f(u.w);
  if (tid < 34) { tile[0][tid] = 0.f; tile[33][tid] = 0.f; }
  if (tid < 32) { tile[tid + 1][0] = 0.f; tile[tid + 1][33] = 0.f; }
  __syncthreads();

  const float* wc = w9 + ch * 9;
  float s[4] = {0.f, 0.f, 0.f, 0.f};
#pragma unroll
  for (int dy = 0; dy < 3; dy++) {
    const float* tr = &tile[y + dy][x0];
    float c0 = tr[0], c1 = tr[1], c2 = tr[2], c3 = tr[3], c4 = tr[4], c5 = tr[5];
    float wa = wc[dy * 3], wb = wc[dy * 3 + 1], wd = wc[dy * 3 + 2];
    s[0] += c0 * wa + c1 * wb + c2 * wd;
    s[1] += c1 * wa + c2 * wb + c3 * wd;
    s[2] += c2 * wa + c3 * wb + c4 * wd;
    s[3] += c3 * wa + c4 * wb + c5 * wd;
  }

  float inv = 1.f;
  if (NORM) {
    float ss = s[0] * s[0] + s[1] * s[1] + s[2] * s[2] + s[3] * s[3];
    ss = wredsum(ss);
    const int lane = tid & 63, wid = tid >> 6;
    if (lane == 0) red[wid] = ss;
    __syncthreads();
    inv = 1.0f / fmaxf(sqrtf(red[0] + red[1] + red[2] + red[3]), 1e-12f);
  }
  ushort4 o4;
  o4.x = f2bfu(s[0] * inv);
  o4.y = f2bfu(s[1] * inv);
  o4.z = f2bfu(s[2] * inv);
  o4.w = f2bfu(s[3] * inv);
  *(ushort4*)(out + ((size_t)bc << 10) + (y << 5) + x0) = o4;
}

// ---------------------------------------------------------------------------
// dwtcast: V path fused depthwise-3x3 + transpose. One pass.
// ---------------------------------------------------------------------------
__global__ void __launch_bounds__(256) dwtcast(const bf16* __restrict__ in,
                                               const float* __restrict__ w9,
                                               bf16* __restrict__ out) {
  __shared__ float t[3][32][34];
  const int jt = blockIdx.x;
  const int y = blockIdx.y;
  const int bh = blockIdx.z;
  const int b = bh >> 2, h = bh & 3;
  const int j0 = jt << 5;
  const int tid = threadIdx.x;

  if (tid < 192) {
    const int rr = tid / 64;
    const int rem = tid - rr * 64;
    const int jc = rem >> 1;
    const int half = rem & 1;
    const int iy = y - 1 + rr;
    float* dstp = &t[rr][jc][1 + (half << 4)];
    if (iy < 0 || iy > 31) {
#pragma unroll
      for (int u = 0; u < 16; u++) dstp[u] = 0.f;
    } else {
      const bf16* src = in + (((ll)b * CKV_ + h * KV_ + j0 + jc) << 10) +
                        (iy << 5) + (half << 4);
      u16x8 v0 = *(const u16x8*)src;
      u16x8 v1 = *(const u16x8*)(src + 8);
#pragma unroll
      for (int u = 0; u < 8; u++) dstp[u] = bfu2f(v0[u]);
#pragma unroll
      for (int u = 0; u < 8; u++) dstp[8 + u] = bfu2f(v1[u]);
    }
  }
  if (tid < 96) {
    const int rr = tid / 32, jc = tid - rr * 32;
    t[rr][jc][0] = 0.f;
    t[rr][jc][33] = 0.f;
  }
  __syncthreads();

  const int jp = tid & 15;
  const int xq = tid >> 4;
  const int ch0 = jp << 1;
  const float* wA = w9 + ((size_t)h * KV_ + j0 + ch0) * 9;
  const float* wB = wA + 9;

  bf16* orow = out + (ll)bh * 983040 + (ll)j0 + (ch0);
#pragma unroll
  for (int sx = 0; sx < 2; sx++) {
    const int x = xq + (sx << 4);
    float sA = 0.f, sB = 0.f;
#pragma unroll
    for (int dy = 0; dy < 3; dy++) {
      const float* rA = &t[dy][ch0][x];
      const float* rB = &t[dy][ch0 + 1][x];
      sA += rA[0] * wA[dy * 3] + rA[1] * wA[dy * 3 + 1] + rA[2] * wA[dy * 3 + 2];
      sB += rB[0] * wB[dy * 3] + rB[1] * wB[dy * 3 + 1] + rB[2] * wB[dy * 3 + 2];
    }
    const int n = (y << 5) + x;
    ushort2 o;
    o.x = f2bfu(sA);
    o.y = f2bfu(sB);
    *(ushort2*)(orow + (ll)n * 960) = o;
  }
}

// ---------------------------------------------------------------------------
// K3: grouped 3x3 (2 in-ch per group) + fused l2norm. 256 thr, 4 px/thread.
// ---------------------------------------------------------------------------
__global__ void __launch_bounds__(256) gq3x3v(const bf16* __restrict__ in,
                                              const float* __restrict__ wq,
                                              bf16* __restrict__ out, int C4) {
  __shared__ float t0[34][36];
  __shared__ float t1[34][36];
  __shared__ float red[4];
  const int bo = blockIdx.x;
  const int o = bo % C4;
  const int b = bo / C4;
  const int ic0 = (o >> 1) << 1;
  const int tid = threadIdx.x;
  const int y = tid >> 3;
  const int x0 = (tid & 7) << 2;
  const bf16* p0 = in + (((size_t)b * C4 + ic0) << 10);

  ushort4 u0 = *(const ushort4*)(p0 + (y << 5) + x0);
  ushort4 u1 = *(const ushort4*)(p0 + 1024 + (y << 5) + x0);
  t0[y + 1][x0 + 1] = bfu2f(u0.x);
  t0[y + 1][x0 + 2] = bfu2f(u0.y);
  t0[y + 1][x0 + 3] = bfu2f(u0.z);
  t0[y + 1][x0 + 4] = bfu2f(u0.w);
  t1[y + 1][x0 + 1] = bfu2f(u1.x);
  t1[y + 1][x0 + 2] = bfu2f(u1.y);
  t1[y + 1][x0 + 3] = bfu2f(u1.z);
  t1[y + 1][x0 + 4] = bfu2f(u1.w);
  if (tid < 34) {
    t0[0][tid] = 0.f; t0[33][tid] = 0.f;
    t1[0][tid] = 0.f; t1[33][tid] = 0.f;
  }
  if (tid < 32) {
    t0[tid + 1][0] = 0.f; t0[tid + 1][33] = 0.f;
    t1[tid + 1][0] = 0.f; t1[tid + 1][33] = 0.f;
  }
  __syncthreads();

  const float* w = wq + o * 18;
  float s[4] = {0.f, 0.f, 0.f, 0.f};
#pragma unroll
  for (int dy = 0; dy < 3; dy++) {
    {
      const float* tr = &t0[y + dy][x0];
      float c0 = tr[0], c1 = tr[1], c2 = tr[2], c3 = tr[3], c4 = tr[4], c5 = tr[5];
      float wa = w[dy * 3], wb = w[dy * 3 + 1], wd = w[dy * 3 + 2];
      s[0] += c0 * wa + c1 * wb + c2 * wd;
      s[1] += c1 * wa + c2 * wb + c3 * wd;
      s[2] += c2 * wa + c3 * wb + c4 * wd;
      s[3] += c3 * wa + c4 * wb + c5 * wd;
    }
    {
      const float* tr = &t1[y + dy][x0];
      float c0 = tr[0], c1 = tr[1], c2 = tr[2], c3 = tr[3], c4 = tr[4], c5 = tr[5];
      float wa = w[9 + dy * 3], wb = w[9 + dy * 3 + 1], wd = w[9 + dy * 3 + 2];
      s[0] += c0 * wa + c1 * wb + c2 * wd;
      s[1] += c1 * wa + c2 * wb + c3 * wd;
      s[2] += c2 * wa + c3 * wb + c4 * wd;
      s[3] += c3 * wa + c4 * wb + c5 * wd;
    }
  }

  float ss = s[0] * s[0] + s[1] * s[1] + s[2] * s[2] + s[3] * s[3];
  ss = wredsum(ss);
  const int lane = tid & 63, wid = tid >> 6;
  if (lane == 0) red[wid] = ss;
  __syncthreads();
  float inv = 1.0f / fmaxf(sqrtf(red[0] + red[1] + red[2] + red[3]), 1e-12f);

  ushort4 o4;
  o4.x = f2bfu(s[0] * inv);
  o4.y = f2bfu(s[1] * inv);
  o4.z = f2bfu(s[2] * inv);
  o4.w = f2bfu(s[3] * inv);
  *(ushort4*)(out + ((size_t)bo << 10) + (y << 5) + x0) = o4;
}

// ---------------------------------------------------------------------------
// K6: row softmax over 960 with inline InstanceNorm stats from partials.
// ---------------------------------------------------------------------------
__global__ void __launch_bounds__(256) softmax_rows(const float* __restrict__ attn,
                                                    const float* __restrict__ part,
                                                    int nslots,
                                                    bf16* __restrict__ probs, int c) {
  __shared__ float rm[4], rs[4];
  const int row = blockIdx.x;
  const int bh = row / c;
  const float* p = attn + (size_t)row * 960;
  bf16* op = probs + (size_t)row * 960;
  const int tid = threadIdx.x;

  float s = 0.f, s2 = 0.f;
  for (int i = 0; i < nslots; i++) {
    s += part[((ll)bh * 32 + i) * 2];
    s2 += part[((ll)bh * 32 + i) * 2 + 1];
  }
  const float n = (float)(c * 960);
  const float mu = s / n;
  const float var = s2 / n - mu * mu;
  const float rstd = rsqrtf(var + 1e-5f);

  float v[4];
  float mx = -1e30f;
#pragma unroll
  for (int u = 0; u < 4; u++) {
    int j = tid + (u << 8);
    if (j < 960) {
      v[u] = (p[j] - mu) * rstd;
      mx = fmaxf(mx, v[u]);
    } else {
      v[u] = -1e30f;
    }
  }
  mx = wredmax(mx);
  const int lane = tid & 63, wid = tid >> 6;
  if (lane == 0) rm[wid] = mx;
  __syncthreads();
  mx = fmaxf(fmaxf(rm[0], rm[1]), fmaxf(rm[2], rm[3]));

  float sum = 0.f;
#pragma unroll
  for (int u = 0; u < 4; u++) {
    int j = tid + (u << 8);
    if (j < 960) {
      v[u] = __expf(v[u] - mx);
      sum += v[u];
    }
  }
  sum = wredsum(sum);
  if (lane == 0) rs[wid] = sum;
  __syncthreads();
  sum = rs[0] + rs[1] + rs[2] + rs[3];
  const float inv = 1.0f / sum;
#pragma unroll
  for (int u = 0; u < 4; u++) {
    int j = tid + (u << 8);
    if (j < 960) op[j] = __float2bfloat16(v[u] * inv);
  }
}

// ---------------------------------------------------------------------------
// Workspace plan — identical to R6..R10 (proven to fit).
// ---------------------------------------------------------------------------
static size_t p4_size(int nb) {
  const int chunkB = (nb + 1) / 2;
  size_t a = (size_t)nb * 4194304;
  size_t b = (size_t)nb * 1966080 + 7372800;
  size_t c = (size_t)chunkB * 7864320;
  size_t m = a > b ? a : b;
  return m > c ? m : c;
}
static size_t p5_size(int nb) {
  size_t a = (size_t)nb * 1048576;
  return a > 7372800 ? a : 7372800;
}
static size_t total_need(int nb) {
  return 3 * (size_t)nb * 7864320 + p4_size(nb) + p5_size(nb) + 3490816;
}

static void run_group(const float* const emb[4], const float* emb_all,
                      const float* const Wq[4],
                      const float* Wmk, const float* Wmv,
                      const float* Wk, const float* Wv,
                      bf16* Wm_all, bf16* Wp_all,
                      float* out, const size_t* out_off,
                      char* ws, int nb, hipStream_t stream) {
  const size_t szBig = (size_t)nb * 7864320;
  char* P1 = ws;
  char* P2 = P1 + szBig;
  char* P3 = P2 + szBig;
  char* P4 = P3 + szBig;
  char* P5 = P4 + p4_size(nb);
  char* FX = P5 + p5_size(nb);

  bf16* kbuf = (bf16*)P1;
  bf16* vt   = (bf16*)P2;
  bf16* kvexp = (bf16*)P3;
  float* attnb = (float*)P3;
  bf16* pvpart = (bf16*)P3;
  bf16* embT_all = (bf16*)P4;
  bf16* Wmv_bf = (bf16*)(P4 + (size_t)nb * 1966080);
  bf16* qbuf = (bf16*)P4;
  bf16* probsb = (bf16*)P4;
  bf16* Wmk_bf = (bf16*)P5;
  bf16* OtT = (bf16*)P5;
  float* part = (float*)(FX + 3482112);

  const float qk_scale = 1.0f / sqrtf((float)KV_);
  const int CHs[4] = {64, 128, 256, 512};
  const size_t wm_off[4] = {0, 16384, 81920, 344064};
  const size_t wp_off[4] = {0, 4096, 20480, 86016};

  // -- prologue: shared K/V --------------------------------------------------
  castw<<<3600, 256, 0, stream>>>(Wmk, Wmk_bf, 3686400);
  castw<<<3600, 256, 0, stream>>>(Wmv, Wmv_bf, 3686400);
  tcast<float><<<dim3(32, 30, nb), 256, 0, stream>>>(emb_all, embT_all, 960,
                                                     983040LL, 983040LL);
  gemm8<1, false><<<dim3(4, 15, nb), 512, 0, stream>>>(
      Wmk_bf, embT_all, kvexp, 3840, 1024, 960, 1, 0, 0, 983040LL, 0,
      3932160LL, 1024, 1.f, nullptr);
  dw3x3v<true><<<nb * CKV_, 256, 0, stream>>>(kvexp, Wk, kbuf, CKV_);
  gemm8<1, false><<<dim3(4, 15, nb), 512, 0, stream>>>(
      Wmv_bf, embT_all, kvexp, 3840, 1024, 960, 1, 0, 0, 983040LL, 0,
      3932160LL, 1024, 1.f, nullptr);
  dwtcast<<<dim3(30, 32, nb * 4), 256, 0, stream>>>(kvexp, Wv, vt);

  // -- branches --------------------------------------------------------------
  for (int br = 0; br < 4; br++) {
    const int c = CHs[br];
    const int C4 = c * 4;
    const int mtiles = (c + 127) / 128;
    bf16* Wm_bf = Wm_all + wm_off[br];
    bf16* Wp_bf = Wp_all + wp_off[br];
    int planeShift = 10;
    for (int t = c; t > 1; t >>= 1) planeShift++;

    tcast<float><<<dim3(32, c / 32, nb), 256, 0, stream>>>(
        emb[br], qbuf, c, (ll)c * 1024, (ll)c * 1024);
    if (c == 512) {
      gemm8<1, false><<<dim3(4, C4 / 256, nb), 512, 0, stream>>>(
          Wm_bf, qbuf, kvexp, C4, 1024, c, 1, 0, 0, (ll)c * 1024, 0,
          (ll)C4 * 1024, 1024, 1.f, nullptr);
    } else {
      gemm_mfma<1, false><<<dim3(8, C4 / 128, nb), 256, 0, stream>>>(
          Wm_bf, qbuf, kvexp, C4, 1024, c, 1, 0, 0, (ll)c * 1024, 0,
          (ll)C4 * 1024, 1024, 1.f, nullptr);
    }
    gq3x3v<<<nb * C4, 256, 0, stream>>>(kvexp, Wq[br], qbuf, C4);
    int nslots;
    if (c == 512) {
      gemm8<0, true><<<dim3(4, c / 256, nb * 4), 512, 0, stream>>>(
          qbuf, kbuf, attnb, c, 960, 1024, 1, (ll)c * 1024, 0, 983040LL, 0,
          (ll)c * 960, 960, qk_scale, part);
      nslots = (c / 256) * 4;
    } else {
      gemm_mfma<0, true><<<dim3(8, mtiles, nb * 4), 256, 0, stream>>>(
          qbuf, kbuf, attnb, c, 960, 1024, 1, (ll)c * 1024, 0, 983040LL, 0,
          (ll)c * 960, 960, qk_scale, part);
      nslots = mtiles * 8;
    }
    softmax_rows<<<nb * 4 * c, 256, 0, stream>>>(attnb, part, nslots, probsb, c);
    if (c == 512) {
      gemm8<2, false><<<dim3(4, c / 256, nb * 4), 512, 0, stream>>>(
          probsb, vt, pvpart, c, 1024, 960, 1, (ll)c * 960, 0, 983040LL, 0,
          (ll)1024 * c, c, 1.f, nullptr);
    } else {
      gemm_mfma<2, false><<<dim3(8, mtiles, nb * 4), 256, 0, stream>>>(
          probsb, vt, pvpart, c, 1024, 960, 1, (ll)c * 960, 0, 983040LL, 0,
          (ll)1024 * c, c, 1.f, nullptr);
    }
    pv_reduce<<<nb * c, 256, 0, stream>>>(pvpart, OtT, planeShift);
    gemm_mfma<0, false><<<dim3(8, mtiles, nb), 256, 0, stream>>>(
        Wp_bf, OtT, out + out_off[br], c, 1024, c, 1, 0, 0,
        (ll)1024 * c, 0, (ll)c * 1024, 1024, 1.f, nullptr);
  }
}

extern "C" void kernel_launch(void* const* d_in, const int* in_sizes, int n_in,
                              void* d_out, int out_size, void* d_ws, size_t ws_size,
                              hipStream_t stream) {
  const float* emb[4] = {(const float*)d_in[0], (const float*)d_in[1],
                         (const float*)d_in[2], (const float*)d_in[3]};
  const float* emb_all = (const float*)d_in[4];
  const float* Wm[4] = {(const float*)d_in[5], (const float*)d_in[8],
                        (const float*)d_in[11], (const float*)d_in[14]};
  const float* Wq[4] = {(const float*)d_in[6], (const float*)d_in[9],
                        (const float*)d_in[12], (const float*)d_in[15]};
  const float* Wp[4] = {(const float*)d_in[7], (const float*)d_in[10],
                        (const float*)d_in[13], (const float*)d_in[16]};
  const float* Wmk = (const float*)d_in[17];
  const float* Wmv = (const float*)d_in[18];
  const float* Wk = (const float*)d_in[19];
  const float* Wv = (const float*)d_in[20];
  float* out = (float*)d_out;

  const int CHs[4] = {64, 128, 256, 512};
  const size_t out_off_full[4] = {0, 524288, 1572864, 3670016};
  const size_t wm_off[4] = {0, 16384, 81920, 344064};
  const size_t wp_off[4] = {0, 4096, 20480, 86016};

  int nb = 1;
  if (ws_size >= total_need(8)) nb = 8;
  else if (ws_size >= total_need(4)) nb = 4;
  else if (ws_size >= total_need(2)) nb = 2;

  char* FX = (char*)d_ws + 3 * (size_t)nb * 7864320 + p4_size(nb) + p5_size(nb);
  bf16* Wm_all = (bf16*)FX;
  bf16* Wp_all = (bf16*)(FX + 2785280);

  for (int br = 0; br < 4; br++) {
    const int c = CHs[br];
    castw<<<(4 * c * c / 4 + 255) / 256, 256, 0, stream>>>(
        Wm[br], Wm_all + wm_off[br], 4 * c * c);
    castw<<<(c * c / 4 + 255) / 256, 256, 0, stream>>>(
        Wp[br], Wp_all + wp_off[br], c * c);
  }

  for (int b0 = 0; b0 < B_; b0 += nb) {
    const float* embB[4];
    for (int i = 0; i < 4; i++) embB[i] = emb[i] + (size_t)b0 * CHs[i] * HW_;
    const float* emb_allB = emb_all + (size_t)b0 * KV_ * HW_;
    size_t out_offB[4];
    for (int i = 0; i < 4; i++)
      out_offB[i] = out_off_full[i] + (size_t)b0 * CHs[i] * HW_;
    run_group(embB, emb_allB, Wq, Wmk, Wmv, Wk, Wv, Wm_all, Wp_all,
              out, out_offB, (char*)d_ws, nb, stream);
  }
}

// Round 12
// 806.650 us; speedup vs baseline: 1.0153x; 1.0153x over previous
//
#include <hip/hip_runtime.h>
#include <hip/hip_bf16.h>
#include <math.h>

typedef __hip_bfloat16 bf16;
typedef __attribute__((ext_vector_type(8))) short short8;
typedef __attribute__((ext_vector_type(8))) unsigned short u16x8;
typedef __attribute__((ext_vector_type(4))) float f32x4;
typedef long long ll;

#define B_ 8
#define HEADS_ 4
#define KV_ 960
#define HW_ 1024
#define CKV_ 3840   // KV_*HEADS_

// ---------------------------------------------------------------------------
// helpers
// ---------------------------------------------------------------------------
__device__ __forceinline__ float wredsum(float v) {
#pragma unroll
  for (int o = 32; o > 0; o >>= 1) v += __shfl_xor(v, o);
  return v;
}
__device__ __forceinline__ float wredmax(float v) {
#pragma unroll
  for (int o = 32; o > 0; o >>= 1) v = fmaxf(v, __shfl_xor(v, o));
  return v;
}

__device__ __forceinline__ float bfu2f(unsigned short u) {
  union { unsigned int i; float f; } c;
  c.i = ((unsigned int)u) << 16;
  return c.f;
}
__device__ __forceinline__ unsigned short f2bfu(float f) {
  bf16 h = __float2bfloat16(f);
  return *(unsigned short*)&h;
}

__device__ __forceinline__ void gl_lds16(const void* g, void* l) {
  __builtin_amdgcn_global_load_lds(
      (const __attribute__((address_space(1))) unsigned*)g,
      (__attribute__((address_space(3))) unsigned*)l, 16, 0, 0);
}

// ---------------------------------------------------------------------------
// K0a: elementwise f32 -> bf16 cast (weights). n % 4 == 0.
// ---------------------------------------------------------------------------
__global__ void __launch_bounds__(256) castw(const float* __restrict__ in,
                                             bf16* __restrict__ out, int n) {
  int i = (blockIdx.x * 256 + threadIdx.x) * 4;
  if (i < n) {
    float4 v = *(const float4*)(in + i);
    out[i] = __float2bfloat16(v.x);
    out[i + 1] = __float2bfloat16(v.y);
    out[i + 2] = __float2bfloat16(v.z);
    out[i + 3] = __float2bfloat16(v.w);
  }
}

// ---------------------------------------------------------------------------
// K0b: transpose+cast: in [z][R][1024] f32 -> out [z][1024][R] bf16.
// ---------------------------------------------------------------------------
template <typename InT>
__global__ void __launch_bounds__(256) tcast(const InT* __restrict__ in,
                                             bf16* __restrict__ out, int R,
                                             ll inZ, ll outZ) {
  __shared__ float t[32][33];
  const int x = threadIdx.x & 31, y0 = threadIdx.x >> 5;
  const int c0 = blockIdx.x << 5, r0 = blockIdx.y << 5;
  const InT* ip = in + (ll)blockIdx.z * inZ + (ll)r0 * 1024 + c0;
  bf16* op = out + (ll)blockIdx.z * outZ + (ll)c0 * R + r0;
#pragma unroll
  for (int i = 0; i < 4; i++) {
    int r = y0 + i * 8;
    float v;
    if constexpr (__is_same(InT, float)) v = ip[(ll)r * 1024 + x];
    else v = __bfloat162float(ip[(ll)r * 1024 + x]);
    t[r][x] = v;
  }
  __syncthreads();
#pragma unroll
  for (int i = 0; i < 4; i++) {
    int cc = y0 + i * 8;
    op[(ll)cc * R + x] = __float2bfloat16(t[x][cc]);
  }
}

// ---------------------------------------------------------------------------
// gemm_mfma: 128x128 / BK=32 / 2-phase dbuf (proven).
// ---------------------------------------------------------------------------
template <int OUTMODE, bool STATS>
__global__ void __launch_bounds__(256) gemm_mfma(
    const bf16* __restrict__ A, const bf16* __restrict__ Bt, void* __restrict__ Y,
    int M, int N, int K, int nh,
    ll aZ, ll aH, ll bZ, ll bH, ll yZ, int ldy, float scale,
    float* __restrict__ part) {
  __shared__ bf16 As[2][128 * 32];
  __shared__ bf16 Bs[2][128 * 32];
  __shared__ float rs1[4], rs2[4];
  const int tid = threadIdx.x;
  const int lane = tid & 63;
  const int wave = tid >> 6;
  const int wr = wave >> 1, wc = wave & 1;

  const int gy = gridDim.y, gz = gridDim.z;
  int orig = (blockIdx.z * gy + blockIdx.y) * 8 + blockIdx.x;
  int cpx = (gy * gz);
  int flat = (orig & 7) * cpx + (orig >> 3);
  const int lx = flat & 7;
  int rest = flat >> 3;
  const int ly = rest % gy;
  const int lz = rest / gy;

  const int z = lz;
  const int m0 = ly << 7, n0 = lx << 7;

  f32x4 acc[4][4];
#pragma unroll
  for (int i = 0; i < 4; i++)
#pragma unroll
    for (int j = 0; j < 4; j++) acc[i][j] = (f32x4){0.f, 0.f, 0.f, 0.f};

  const int frow = lane & 15;
  const int kq = lane >> 4;

  const bf16* Ah = A + (ll)z * aZ;
  const bf16* Bh = Bt + (ll)z * bZ;
  int k0n = 0;

  auto stage = [&](int buf) {
#pragma unroll
    for (int t = 0; t < 2; t++) {
      const int e = (wave * 2 + t) * 64 + lane;
      const int row = e >> 2;
      const int ks = (e & 3) ^ ((row >> 1) & 3);
      int gr = m0 + row; gr = gr < M ? gr : M - 1;
      gl_lds16(Ah + (ll)gr * K + k0n + ks * 8,
               (char*)&As[buf][0] + (wave * 2 + t) * 1024);
      int rn = n0 + row; rn = rn < N ? rn : N - 1;
      gl_lds16(Bh + (ll)rn * K + k0n + ks * 8,
               (char*)&Bs[buf][0] + (wave * 2 + t) * 1024);
    }
  };

  const int kpt = K >> 5;
  const int iters = nh * kpt;
  stage(0);
  __syncthreads();

  int buf = 0;
  for (int it = 0; it < iters; ++it) {
    if (it + 1 < iters) {
      k0n += 32;
      if (k0n == K) { k0n = 0; Ah += aH; Bh += bH; }
      stage(buf ^ 1);
    }
    short8 af[4], bfr[4];
#pragma unroll
    for (int fm = 0; fm < 4; fm++) {
      const int row = wr * 64 + fm * 16 + frow;
      af[fm] = *(const short8*)&As[buf][((row << 2) | (kq ^ ((row >> 1) & 3))) << 3];
    }
#pragma unroll
    for (int fn = 0; fn < 4; fn++) {
      const int row = wc * 64 + fn * 16 + frow;
      bfr[fn] = *(const short8*)&Bs[buf][((row << 2) | (kq ^ ((row >> 1) & 3))) << 3];
    }
#pragma unroll
    for (int fm = 0; fm < 4; fm++)
#pragma unroll
      for (int fn = 0; fn < 4; fn++)
        acc[fm][fn] = __builtin_amdgcn_mfma_f32_16x16x32_bf16(
            af[fm], bfr[fn], acc[fm][fn], 0, 0, 0);
    __syncthreads();
    buf ^= 1;
  }

  const int rq = kq << 2;
  float lsum = 0.f, lsq = 0.f;
#pragma unroll
  for (int fm = 0; fm < 4; fm++) {
    const int mrow = m0 + wr * 64 + fm * 16 + rq;
#pragma unroll
    for (int fn = 0; fn < 4; fn++) {
      const int ncol = n0 + wc * 64 + fn * 16 + frow;
      if (ncol >= N) continue;
      if constexpr (OUTMODE == 0) {
        float* Yp = (float*)Y + (ll)z * yZ;
#pragma unroll
        for (int i = 0; i < 4; i++)
          if (mrow + i < M) {
            float v = acc[fm][fn][i] * scale;
            Yp[(ll)(mrow + i) * ldy + ncol] = v;
            if constexpr (STATS) { lsum += v; lsq += v * v; }
          }
      } else if constexpr (OUTMODE == 1) {
        bf16* Yp = (bf16*)Y + (ll)z * yZ;
#pragma unroll
        for (int i = 0; i < 4; i++)
          if (mrow + i < M)
            Yp[(ll)(mrow + i) * ldy + ncol] =
                __float2bfloat16(acc[fm][fn][i] * scale);
      } else {
        if (mrow < M) {
          bf16* Yp = (bf16*)Y + (ll)z * yZ + (ll)ncol * ldy + mrow;
#pragma unroll
          for (int i = 0; i < 4; i++)
            Yp[i] = __float2bfloat16(acc[fm][fn][i] * scale);
        }
      }
    }
  }
  if constexpr (STATS) {
    lsum = wredsum(lsum);
    lsq = wredsum(lsq);
    if (lane == 0) { rs1[wave] = lsum; rs2[wave] = lsq; }
    __syncthreads();
    if (tid == 0) {
      int slot = ly * 8 + lx;
      part[((ll)z * 32 + slot) * 2] = rs1[0] + rs1[1] + rs1[2] + rs1[3];
      part[((ll)z * 32 + slot) * 2 + 1] = rs2[0] + rs2[1] + rs2[2] + rs2[3];
    }
  }
}

// ---------------------------------------------------------------------------
// gemm8: 256x256, BK=64, 512 thr, dbuf, 4-phase schedule (R10-proven) with
// R12 front-loaded staging: p0 issues all 4 B-rounds of tile t+1, p1 issues
// A r0,r2, p2 issues A r1,r3 -> every load gets 3-4 phases of latency slack.
// Requirement sets (hand-verified): {B all, A r0,r2}@p0 -> vmcnt(2);
// {A r1,r3}@p2 -> vmcnt(6) (they are the 2 oldest of 8 outstanding).
// ---------------------------------------------------------------------------
template <int OUTMODE, bool STATS>
__global__ void __launch_bounds__(512, 2) gemm8(
    const bf16* __restrict__ A, const bf16* __restrict__ Bt, void* __restrict__ Y,
    int M, int N, int K, int nh,
    ll aZ, ll aH, ll bZ, ll bH, ll yZ, int ldy, float scale,
    float* __restrict__ part) {
  __shared__ char lds[131072];           // [A0|A1|B0|B1] each 32KB
  __shared__ float rs1[8], rs2[8];
  const int tid = threadIdx.x;
  const int lane = tid & 63;
  const int wave = tid >> 6;
  const int wm = wave >> 2, wn = wave & 3;

  const int nx = gridDim.x, my = gridDim.y;
  const int nwg = nx * my * gridDim.z;
  int orig = (blockIdx.z * my + blockIdx.y) * nx + blockIdx.x;
  int q8 = nwg >> 3, r8 = nwg & 7;
  int xcd = orig & 7, bidx = orig >> 3;
  int flat = (xcd < r8) ? xcd * (q8 + 1) + bidx
                        : r8 * (q8 + 1) + (xcd - r8) * q8 + bidx;
  const int lx = flat % nx;
  int rest = flat / nx;
  const int ly = rest % my;
  const int lz = rest / my;

  const int m0 = ly << 8, n0 = lx << 8;
  const int ktiles = K >> 6;
  const int nt = nh * ktiles;

  f32x4 acc[8][4];
#pragma unroll
  for (int i = 0; i < 8; i++)
#pragma unroll
    for (int j = 0; j < 4; j++) acc[i][j] = (f32x4){0.f, 0.f, 0.f, 0.f};

  const int frow = lane & 15;
  const int kq = lane >> 4;
  const int swz = frow & 7;

  auto stageRound = [&](int matB, int r, int tt, int buf) {
    int h = tt / ktiles;
    int koff = (tt % ktiles) << 6;
    int s = (r << 9) + tid;
    int row = s >> 3;
    int ks = (s & 7) ^ (row & 7);
    const bf16* src;
    char* dst;
    if (!matB) {
      int gr = m0 + row; gr = gr < M ? gr : M - 1;
      src = A + (ll)lz * aZ + (ll)h * aH + (ll)gr * K + koff + (ks << 3);
      dst = lds + buf * 32768 + (((r << 3) + wave) << 10);
    } else {
      int gr = n0 + row; gr = gr < N ? gr : N - 1;
      src = Bt + (ll)lz * bZ + (ll)h * bH + (ll)gr * K + koff + (ks << 3);
      dst = lds + 65536 + buf * 32768 + (((r << 3) + wave) << 10);
    }
    gl_lds16(src, dst);
  };

  auto readA = [&](int fm, int kh, int cur) -> short8 {
    int row = wm * 128 + fm * 16 + frow;
    int slot = (kq + (kh << 2)) ^ swz;
    return *(const short8*)(lds + cur * 32768 + row * 128 + slot * 16);
  };
  auto readB = [&](int fn, int kh, int cur) -> short8 {
    int row = wn * 64 + fn * 16 + frow;
    int slot = (kq + (kh << 2)) ^ swz;
    return *(const short8*)(lds + 65536 + cur * 32768 + row * 128 + slot * 16);
  };

  // prologue: tile 0 in steady-state order: B r0-3, A r0, A r2, A r1, A r3
  stageRound(1, 0, 0, 0); stageRound(1, 1, 0, 0);
  stageRound(1, 2, 0, 0); stageRound(1, 3, 0, 0);
  stageRound(0, 0, 0, 0); stageRound(0, 2, 0, 0);
  stageRound(0, 1, 0, 0); stageRound(0, 3, 0, 0);

  int cur = 0;
  for (int tt = 0; tt < nt; ++tt) {
    const bool hasNext = (tt + 1 < nt);
    short8 bfr[4][2];
#pragma unroll
    for (int p = 0; p < 4; p++) {
      if (p == 0) {
        if (hasNext) asm volatile("s_waitcnt vmcnt(2)" ::: "memory");
        else         asm volatile("s_waitcnt vmcnt(0)" ::: "memory");
        __builtin_amdgcn_s_barrier();
        __builtin_amdgcn_sched_barrier(0);
#pragma unroll
        for (int fn = 0; fn < 4; fn++)
#pragma unroll
          for (int kh = 0; kh < 2; kh++) bfr[fn][kh] = readB(fn, kh, cur);
      }
      if (p == 2) {
        if (hasNext) asm volatile("s_waitcnt vmcnt(6)" ::: "memory");
        __builtin_amdgcn_s_barrier();
        __builtin_amdgcn_sched_barrier(0);
      }
      short8 a0k0 = readA(2 * p, 0, cur), a0k1 = readA(2 * p, 1, cur);
      short8 a1k0 = readA(2 * p + 1, 0, cur), a1k1 = readA(2 * p + 1, 1, cur);
      if (hasNext) {
        if (p == 0) {
          stageRound(1, 0, tt + 1, cur ^ 1); stageRound(1, 1, tt + 1, cur ^ 1);
          stageRound(1, 2, tt + 1, cur ^ 1); stageRound(1, 3, tt + 1, cur ^ 1);
        } else if (p == 1) {
          stageRound(0, 0, tt + 1, cur ^ 1); stageRound(0, 2, tt + 1, cur ^ 1);
        } else if (p == 2) {
          stageRound(0, 1, tt + 1, cur ^ 1); stageRound(0, 3, tt + 1, cur ^ 1);
        }
      }
      __builtin_amdgcn_s_setprio(1);
#pragma unroll
      for (int fn = 0; fn < 4; fn++) {
        acc[2 * p][fn] = __builtin_amdgcn_mfma_f32_16x16x32_bf16(
            a0k0, bfr[fn][0], acc[2 * p][fn], 0, 0, 0);
        acc[2 * p][fn] = __builtin_amdgcn_mfma_f32_16x16x32_bf16(
            a0k1, bfr[fn][1], acc[2 * p][fn], 0, 0, 0);
        acc[2 * p + 1][fn] = __builtin_amdgcn_mfma_f32_16x16x32_bf16(
            a1k0, bfr[fn][0], acc[2 * p + 1][fn], 0, 0, 0);
        acc[2 * p + 1][fn] = __builtin_amdgcn_mfma_f32_16x16x32_bf16(
            a1k1, bfr[fn][1], acc[2 * p + 1][fn], 0, 0, 0);
      }
      __builtin_amdgcn_s_setprio(0);
    }
    cur ^= 1;
  }

  const int rq = kq << 2;
  float lsum = 0.f, lsq = 0.f;
#pragma unroll
  for (int fm = 0; fm < 8; fm++) {
    const int mrow = m0 + wm * 128 + fm * 16 + rq;
#pragma unroll
    for (int fn = 0; fn < 4; fn++) {
      const int ncol = n0 + wn * 64 + fn * 16 + frow;
      if (ncol >= N) continue;
      if constexpr (OUTMODE == 0) {
        float* Yp = (float*)Y + (ll)lz * yZ;
#pragma unroll
        for (int i = 0; i < 4; i++)
          if (mrow + i < M) {
            float v = acc[fm][fn][i] * scale;
            Yp[(ll)(mrow + i) * ldy + ncol] = v;
            if constexpr (STATS) { lsum += v; lsq += v * v; }
          }
      } else if constexpr (OUTMODE == 1) {
        bf16* Yp = (bf16*)Y + (ll)lz * yZ;
#pragma unroll
        for (int i = 0; i < 4; i++)
          if (mrow + i < M)
            Yp[(ll)(mrow + i) * ldy + ncol] =
                __float2bfloat16(acc[fm][fn][i] * scale);
      } else {
        if (mrow < M) {
          bf16* Yp = (bf16*)Y + (ll)lz * yZ + (ll)ncol * ldy + mrow;
#pragma unroll
          for (int i = 0; i < 4; i++)
            Yp[i] = __float2bfloat16(acc[fm][fn][i] * scale);
        }
      }
    }
  }
  if constexpr (STATS) {
    lsum = wredsum(lsum);
    lsq = wredsum(lsq);
    if (lane == 0) { rs1[wave] = lsum; rs2[wave] = lsq; }
    __syncthreads();
    if (tid == 0) {
      float s = 0.f, s2 = 0.f;
#pragma unroll
      for (int w = 0; w < 8; w++) { s += rs1[w]; s2 += rs2[w]; }
      int slot = ly * nx + lx;
      part[((ll)lz * 32 + slot) * 2] = s;
      part[((ll)lz * 32 + slot) * 2 + 1] = s2;
    }
  }
}

// ---------------------------------------------------------------------------
// pv_reduce: OtT[b][off] = 0.25 * sum_{s<4} part[(b*4+s)][off]  (bf16)
// ---------------------------------------------------------------------------
__global__ void __launch_bounds__(256) pv_reduce(const bf16* __restrict__ part,
                                                 bf16* __restrict__ out,
                                                 int planeShift) {
  const ll idx = ((ll)blockIdx.x * 256 + threadIdx.x) * 4;
  const int b = (int)(idx >> planeShift);
  const ll off = idx - ((ll)b << planeShift);
  const bf16* base = part + (((ll)b * 4) << planeShift) + off;
  float a0 = 0.f, a1 = 0.f, a2 = 0.f, a3 = 0.f;
#pragma unroll
  for (int s = 0; s < 4; s++) {
    ushort4 u = *(const ushort4*)(base + ((ll)s << planeShift));
    a0 += bfu2f(u.x); a1 += bfu2f(u.y); a2 += bfu2f(u.z); a3 += bfu2f(u.w);
  }
  ushort4 o;
  o.x = f2bfu(a0 * 0.25f);
  o.y = f2bfu(a1 * 0.25f);
  o.z = f2bfu(a2 * 0.25f);
  o.w = f2bfu(a3 * 0.25f);
  *(ushort4*)(out + idx) = o;
}

// ---------------------------------------------------------------------------
// K2: depthwise 3x3 (pad 1), optional fused l2norm. 256 thr, 4 px/thread.
// ---------------------------------------------------------------------------
template <bool NORM>
__global__ void __launch_bounds__(256) dw3x3v(const bf16* __restrict__ in,
                                              const float* __restrict__ w9,
                                              bf16* __restrict__ out, int C) {
  __shared__ float tile[34][36];
  __shared__ float red[4];
  const int bc = blockIdx.x;
  const int ch = bc % C;
  const int tid = threadIdx.x;
  const int y = tid >> 3;
  const int x0 = (tid & 7) << 2;
  const bf16* ip = in + ((size_t)bc << 10);

  ushort4 u = *(const ushort4*)(ip + (y << 5) + x0);
  tile[y + 1][x0 + 1] = bfu2f(u.x);
  tile[y + 1][x0 + 2] = bfu2f(u.y);
  tile[y + 1][x0 + 3] = bfu2f(u.z);
  tile[y + 1][x0 + 4] = bfu2f(u.w);
  if (tid < 34) { tile[0][tid] = 0.f; tile[33][tid] = 0.f; }
  if (tid < 32) { tile[tid + 1][0] = 0.f; tile[tid + 1][33] = 0.f; }
  __syncthreads();

  const float* wc = w9 + ch * 9;
  float s[4] = {0.f, 0.f, 0.f, 0.f};
#pragma unroll
  for (int dy = 0; dy < 3; dy++) {
    const float* tr = &tile[y + dy][x0];
    float c0 = tr[0], c1 = tr[1], c2 = tr[2], c3 = tr[3], c4 = tr[4], c5 = tr[5];
    float wa = wc[dy * 3], wb = wc[dy * 3 + 1], wd = wc[dy * 3 + 2];
    s[0] += c0 * wa + c1 * wb + c2 * wd;
    s[1] += c1 * wa + c2 * wb + c3 * wd;
    s[2] += c2 * wa + c3 * wb + c4 * wd;
    s[3] += c3 * wa + c4 * wb + c5 * wd;
  }

  float inv = 1.f;
  if (NORM) {
    float ss = s[0] * s[0] + s[1] * s[1] + s[2] * s[2] + s[3] * s[3];
    ss = wredsum(ss);
    const int lane = tid & 63, wid = tid >> 6;
    if (lane == 0) red[wid] = ss;
    __syncthreads();
    inv = 1.0f / fmaxf(sqrtf(red[0] + red[1] + red[2] + red[3]), 1e-12f);
  }
  ushort4 o4;
  o4.x = f2bfu(s[0] * inv);
  o4.y = f2bfu(s[1] * inv);
  o4.z = f2bfu(s[2] * inv);
  o4.w = f2bfu(s[3] * inv);
  *(ushort4*)(out + ((size_t)bc << 10) + (y << 5) + x0) = o4;
}

// ---------------------------------------------------------------------------
// dwtcast: V path fused depthwise-3x3 + transpose. One pass.
// ---------------------------------------------------------------------------
__global__ void __launch_bounds__(256) dwtcast(const bf16* __restrict__ in,
                                               const float* __restrict__ w9,
                                               bf16* __restrict__ out) {
  __shared__ float t[3][32][34];
  const int jt = blockIdx.x;
  const int y = blockIdx.y;
  const int bh = blockIdx.z;
  const int b = bh >> 2, h = bh & 3;
  const int j0 = jt << 5;
  const int tid = threadIdx.x;

  if (tid < 192) {
    const int rr = tid / 64;
    const int rem = tid - rr * 64;
    const int jc = rem >> 1;
    const int half = rem & 1;
    const int iy = y - 1 + rr;
    float* dstp = &t[rr][jc][1 + (half << 4)];
    if (iy < 0 || iy > 31) {
#pragma unroll
      for (int u = 0; u < 16; u++) dstp[u] = 0.f;
    } else {
      const bf16* src = in + (((ll)b * CKV_ + h * KV_ + j0 + jc) << 10) +
                        (iy << 5) + (half << 4);
      u16x8 v0 = *(const u16x8*)src;
      u16x8 v1 = *(const u16x8*)(src + 8);
#pragma unroll
      for (int u = 0; u < 8; u++) dstp[u] = bfu2f(v0[u]);
#pragma unroll
      for (int u = 0; u < 8; u++) dstp[8 + u] = bfu2f(v1[u]);
    }
  }
  if (tid < 96) {
    const int rr = tid / 32, jc = tid - rr * 32;
    t[rr][jc][0] = 0.f;
    t[rr][jc][33] = 0.f;
  }
  __syncthreads();

  const int jp = tid & 15;
  const int xq = tid >> 4;
  const int ch0 = jp << 1;
  const float* wA = w9 + ((size_t)h * KV_ + j0 + ch0) * 9;
  const float* wB = wA + 9;

  bf16* orow = out + (ll)bh * 983040 + (ll)j0 + (ch0);
#pragma unroll
  for (int sx = 0; sx < 2; sx++) {
    const int x = xq + (sx << 4);
    float sA = 0.f, sB = 0.f;
#pragma unroll
    for (int dy = 0; dy < 3; dy++) {
      const float* rA = &t[dy][ch0][x];
      const float* rB = &t[dy][ch0 + 1][x];
      sA += rA[0] * wA[dy * 3] + rA[1] * wA[dy * 3 + 1] + rA[2] * wA[dy * 3 + 2];
      sB += rB[0] * wB[dy * 3] + rB[1] * wB[dy * 3 + 1] + rB[2] * wB[dy * 3 + 2];
    }
    const int n = (y << 5) + x;
    ushort2 o;
    o.x = f2bfu(sA);
    o.y = f2bfu(sB);
    *(ushort2*)(orow + (ll)n * 960) = o;
  }
}

// ---------------------------------------------------------------------------
// K3: grouped 3x3 (2 in-ch per group) + fused l2norm. 256 thr, 4 px/thread.
// ---------------------------------------------------------------------------
__global__ void __launch_bounds__(256) gq3x3v(const bf16* __restrict__ in,
                                              const float* __restrict__ wq,
                                              bf16* __restrict__ out, int C4) {
  __shared__ float t0[34][36];
  __shared__ float t1[34][36];
  __shared__ float red[4];
  const int bo = blockIdx.x;
  const int o = bo % C4;
  const int b = bo / C4;
  const int ic0 = (o >> 1) << 1;
  const int tid = threadIdx.x;
  const int y = tid >> 3;
  const int x0 = (tid & 7) << 2;
  const bf16* p0 = in + (((size_t)b * C4 + ic0) << 10);

  ushort4 u0 = *(const ushort4*)(p0 + (y << 5) + x0);
  ushort4 u1 = *(const ushort4*)(p0 + 1024 + (y << 5) + x0);
  t0[y + 1][x0 + 1] = bfu2f(u0.x);
  t0[y + 1][x0 + 2] = bfu2f(u0.y);
  t0[y + 1][x0 + 3] = bfu2f(u0.z);
  t0[y + 1][x0 + 4] = bfu2f(u0.w);
  t1[y + 1][x0 + 1] = bfu2f(u1.x);
  t1[y + 1][x0 + 2] = bfu2f(u1.y);
  t1[y + 1][x0 + 3] = bfu2f(u1.z);
  t1[y + 1][x0 + 4] = bfu2f(u1.w);
  if (tid < 34) {
    t0[0][tid] = 0.f; t0[33][tid] = 0.f;
    t1[0][tid] = 0.f; t1[33][tid] = 0.f;
  }
  if (tid < 32) {
    t0[tid + 1][0] = 0.f; t0[tid + 1][33] = 0.f;
    t1[tid + 1][0] = 0.f; t1[tid + 1][33] = 0.f;
  }
  __syncthreads();

  const float* w = wq + o * 18;
  float s[4] = {0.f, 0.f, 0.f, 0.f};
#pragma unroll
  for (int dy = 0; dy < 3; dy++) {
    {
      const float* tr = &t0[y + dy][x0];
      float c0 = tr[0], c1 = tr[1], c2 = tr[2], c3 = tr[3], c4 = tr[4], c5 = tr[5];
      float wa = w[dy * 3], wb = w[dy * 3 + 1], wd = w[dy * 3 + 2];
      s[0] += c0 * wa + c1 * wb + c2 * wd;
      s[1] += c1 * wa + c2 * wb + c3 * wd;
      s[2] += c2 * wa + c3 * wb + c4 * wd;
      s[3] += c3 * wa + c4 * wb + c5 * wd;
    }
    {
      const float* tr = &t1[y + dy][x0];
      float c0 = tr[0], c1 = tr[1], c2 = tr[2], c3 = tr[3], c4 = tr[4], c5 = tr[5];
      float wa = w[9 + dy * 3], wb = w[9 + dy * 3 + 1], wd = w[9 + dy * 3 + 2];
      s[0] += c0 * wa + c1 * wb + c2 * wd;
      s[1] += c1 * wa + c2 * wb + c3 * wd;
      s[2] += c2 * wa + c3 * wb + c4 * wd;
      s[3] += c3 * wa + c4 * wb + c5 * wd;
    }
  }

  float ss = s[0] * s[0] + s[1] * s[1] + s[2] * s[2] + s[3] * s[3];
  ss = wredsum(ss);
  const int lane = tid & 63, wid = tid >> 6;
  if (lane == 0) red[wid] = ss;
  __syncthreads();
  float inv = 1.0f / fmaxf(sqrtf(red[0] + red[1] + red[2] + red[3]), 1e-12f);

  ushort4 o4;
  o4.x = f2bfu(s[0] * inv);
  o4.y = f2bfu(s[1] * inv);
  o4.z = f2bfu(s[2] * inv);
  o4.w = f2bfu(s[3] * inv);
  *(ushort4*)(out + ((size_t)bo << 10) + (y << 5) + x0) = o4;
}

// ---------------------------------------------------------------------------
// K6: row softmax over 960 with inline InstanceNorm stats from partials.
// ---------------------------------------------------------------------------
__global__ void __launch_bounds__(256) softmax_rows(const float* __restrict__ attn,
                                                    const float* __restrict__ part,
                                                    int nslots,
                                                    bf16* __restrict__ probs, int c) {
  __shared__ float rm[4], rs[4];
  const int row = blockIdx.x;
  const int bh = row / c;
  const float* p = attn + (size_t)row * 960;
  bf16* op = probs + (size_t)row * 960;
  const int tid = threadIdx.x;

  float s = 0.f, s2 = 0.f;
  for (int i = 0; i < nslots; i++) {
    s += part[((ll)bh * 32 + i) * 2];
    s2 += part[((ll)bh * 32 + i) * 2 + 1];
  }
  const float n = (float)(c * 960);
  const float mu = s / n;
  const float var = s2 / n - mu * mu;
  const float rstd = rsqrtf(var + 1e-5f);

  float v[4];
  float mx = -1e30f;
#pragma unroll
  for (int u = 0; u < 4; u++) {
    int j = tid + (u << 8);
    if (j < 960) {
      v[u] = (p[j] - mu) * rstd;
      mx = fmaxf(mx, v[u]);
    } else {
      v[u] = -1e30f;
    }
  }
  mx = wredmax(mx);
  const int lane = tid & 63, wid = tid >> 6;
  if (lane == 0) rm[wid] = mx;
  __syncthreads();
  mx = fmaxf(fmaxf(rm[0], rm[1]), fmaxf(rm[2], rm[3]));

  float sum = 0.f;
#pragma unroll
  for (int u = 0; u < 4; u++) {
    int j = tid + (u << 8);
    if (j < 960) {
      v[u] = __expf(v[u] - mx);
      sum += v[u];
    }
  }
  sum = wredsum(sum);
  if (lane == 0) rs[wid] = sum;
  __syncthreads();
  sum = rs[0] + rs[1] + rs[2] + rs[3];
  const float inv = 1.0f / sum;
#pragma unroll
  for (int u = 0; u < 4; u++) {
    int j = tid + (u << 8);
    if (j < 960) op[j] = __float2bfloat16(v[u] * inv);
  }
}

// ---------------------------------------------------------------------------
// Workspace plan — identical to R6..R10 (proven to fit).
// ---------------------------------------------------------------------------
static size_t p4_size(int nb) {
  const int chunkB = (nb + 1) / 2;
  size_t a = (size_t)nb * 4194304;
  size_t b = (size_t)nb * 1966080 + 7372800;
  size_t c = (size_t)chunkB * 7864320;
  size_t m = a > b ? a : b;
  return m > c ? m : c;
}
static size_t p5_size(int nb) {
  size_t a = (size_t)nb * 1048576;
  return a > 7372800 ? a : 7372800;
}
static size_t total_need(int nb) {
  return 3 * (size_t)nb * 7864320 + p4_size(nb) + p5_size(nb) + 3490816;
}

static void run_group(const float* const emb[4], const float* emb_all,
                      const float* const Wq[4],
                      const float* Wmk, const float* Wmv,
                      const float* Wk, const float* Wv,
                      bf16* Wm_all, bf16* Wp_all,
                      float* out, const size_t* out_off,
                      char* ws, int nb, hipStream_t stream) {
  const size_t szBig = (size_t)nb * 7864320;
  char* P1 = ws;
  char* P2 = P1 + szBig;
  char* P3 = P2 + szBig;
  char* P4 = P3 + szBig;
  char* P5 = P4 + p4_size(nb);
  char* FX = P5 + p5_size(nb);

  bf16* kbuf = (bf16*)P1;
  bf16* vt   = (bf16*)P2;
  bf16* kvexp = (bf16*)P3;
  float* attnb = (float*)P3;
  bf16* pvpart = (bf16*)P3;
  bf16* embT_all = (bf16*)P4;
  bf16* Wmv_bf = (bf16*)(P4 + (size_t)nb * 1966080);
  bf16* qbuf = (bf16*)P4;
  bf16* probsb = (bf16*)P4;
  bf16* Wmk_bf = (bf16*)P5;
  bf16* OtT = (bf16*)P5;
  float* part = (float*)(FX + 3482112);

  const float qk_scale = 1.0f / sqrtf((float)KV_);
  const int CHs[4] = {64, 128, 256, 512};
  const size_t wm_off[4] = {0, 16384, 81920, 344064};
  const size_t wp_off[4] = {0, 4096, 20480, 86016};

  // -- prologue: shared K/V --------------------------------------------------
  castw<<<3600, 256, 0, stream>>>(Wmk, Wmk_bf, 3686400);
  castw<<<3600, 256, 0, stream>>>(Wmv, Wmv_bf, 3686400);
  tcast<float><<<dim3(32, 30, nb), 256, 0, stream>>>(emb_all, embT_all, 960,
                                                     983040LL, 983040LL);
  gemm8<1, false><<<dim3(4, 15, nb), 512, 0, stream>>>(
      Wmk_bf, embT_all, kvexp, 3840, 1024, 960, 1, 0, 0, 983040LL, 0,
      3932160LL, 1024, 1.f, nullptr);
  dw3x3v<true><<<nb * CKV_, 256, 0, stream>>>(kvexp, Wk, kbuf, CKV_);
  gemm8<1, false><<<dim3(4, 15, nb), 512, 0, stream>>>(
      Wmv_bf, embT_all, kvexp, 3840, 1024, 960, 1, 0, 0, 983040LL, 0,
      3932160LL, 1024, 1.f, nullptr);
  dwtcast<<<dim3(30, 32, nb * 4), 256, 0, stream>>>(kvexp, Wv, vt);

  // -- branches --------------------------------------------------------------
  for (int br = 0; br < 4; br++) {
    const int c = CHs[br];
    const int C4 = c * 4;
    const int mtiles = (c + 127) / 128;
    bf16* Wm_bf = Wm_all + wm_off[br];
    bf16* Wp_bf = Wp_all + wp_off[br];
    int planeShift = 10;
    for (int t = c; t > 1; t >>= 1) planeShift++;

    tcast<float><<<dim3(32, c / 32, nb), 256, 0, stream>>>(
        emb[br], qbuf, c, (ll)c * 1024, (ll)c * 1024);
    if (c == 512) {
      gemm8<1, false><<<dim3(4, C4 / 256, nb), 512, 0, stream>>>(
          Wm_bf, qbuf, kvexp, C4, 1024, c, 1, 0, 0, (ll)c * 1024, 0,
          (ll)C4 * 1024, 1024, 1.f, nullptr);
    } else {
      gemm_mfma<1, false><<<dim3(8, C4 / 128, nb), 256, 0, stream>>>(
          Wm_bf, qbuf, kvexp, C4, 1024, c, 1, 0, 0, (ll)c * 1024, 0,
          (ll)C4 * 1024, 1024, 1.f, nullptr);
    }
    gq3x3v<<<nb * C4, 256, 0, stream>>>(kvexp, Wq[br], qbuf, C4);
    int nslots;
    if (c == 512) {
      gemm8<0, true><<<dim3(4, c / 256, nb * 4), 512, 0, stream>>>(
          qbuf, kbuf, attnb, c, 960, 1024, 1, (ll)c * 1024, 0, 983040LL, 0,
          (ll)c * 960, 960, qk_scale, part);
      nslots = (c / 256) * 4;
    } else {
      gemm_mfma<0, true><<<dim3(8, mtiles, nb * 4), 256, 0, stream>>>(
          qbuf, kbuf, attnb, c, 960, 1024, 1, (ll)c * 1024, 0, 983040LL, 0,
          (ll)c * 960, 960, qk_scale, part);
      nslots = mtiles * 8;
    }
    softmax_rows<<<nb * 4 * c, 256, 0, stream>>>(attnb, part, nslots, probsb, c);
    if (c == 512) {
      gemm8<2, false><<<dim3(4, c / 256, nb * 4), 512, 0, stream>>>(
          probsb, vt, pvpart, c, 1024, 960, 1, (ll)c * 960, 0, 983040LL, 0,
          (ll)1024 * c, c, 1.f, nullptr);
    } else {
      gemm_mfma<2, false><<<dim3(8, mtiles, nb * 4), 256, 0, stream>>>(
          probsb, vt, pvpart, c, 1024, 960, 1, (ll)c * 960, 0, 983040LL, 0,
          (ll)1024 * c, c, 1.f, nullptr);
    }
    pv_reduce<<<nb * c, 256, 0, stream>>>(pvpart, OtT, planeShift);
    gemm_mfma<0, false><<<dim3(8, mtiles, nb), 256, 0, stream>>>(
        Wp_bf, OtT, out + out_off[br], c, 1024, c, 1, 0, 0,
        (ll)1024 * c, 0, (ll)c * 1024, 1024, 1.f, nullptr);
  }
}

extern "C" void kernel_launch(void* const* d_in, const int* in_sizes, int n_in,
                              void* d_out, int out_size, void* d_ws, size_t ws_size,
                              hipStream_t stream) {
  const float* emb[4] = {(const float*)d_in[0], (const float*)d_in[1],
                         (const float*)d_in[2], (const float*)d_in[3]};
  const float* emb_all = (const float*)d_in[4];
  const float* Wm[4] = {(const float*)d_in[5], (const float*)d_in[8],
                        (const float*)d_in[11], (const float*)d_in[14]};
  const float* Wq[4] = {(const float*)d_in[6], (const float*)d_in[9],
                        (const float*)d_in[12], (const float*)d_in[15]};
  const float* Wp[4] = {(const float*)d_in[7], (const float*)d_in[10],
                        (const float*)d_in[13], (const float*)d_in[16]};
  const float* Wmk = (const float*)d_in[17];
  const float* Wmv = (const float*)d_in[18];
  const float* Wk = (const float*)d_in[19];
  const float* Wv = (const float*)d_in[20];
  float* out = (float*)d_out;

  const int CHs[4] = {64, 128, 256, 512};
  const size_t out_off_full[4] = {0, 524288, 1572864, 3670016};
  const size_t wm_off[4] = {0, 16384, 81920, 344064};
  const size_t wp_off[4] = {0, 4096, 20480, 86016};

  int nb = 1;
  if (ws_size >= total_need(8)) nb = 8;
  else if (ws_size >= total_need(4)) nb = 4;
  else if (ws_size >= total_need(2)) nb = 2;

  char* FX = (char*)d_ws + 3 * (size_t)nb * 7864320 + p4_size(nb) + p5_size(nb);
  bf16* Wm_all = (bf16*)FX;
  bf16* Wp_all = (bf16*)(FX + 2785280);

  for (int br = 0; br < 4; br++) {
    const int c = CHs[br];
    castw<<<(4 * c * c / 4 + 255) / 256, 256, 0, stream>>>(
        Wm[br], Wm_all + wm_off[br], 4 * c * c);
    castw<<<(c * c / 4 + 255) / 256, 256, 0, stream>>>(
        Wp[br], Wp_all + wp_off[br], c * c);
  }

  for (int b0 = 0; b0 < B_; b0 += nb) {
    const float* embB[4];
    for (int i = 0; i < 4; i++) embB[i] = emb[i] + (size_t)b0 * CHs[i] * HW_;
    const float* emb_allB = emb_all + (size_t)b0 * KV_ * HW_;
    size_t out_offB[4];
    for (int i = 0; i < 4; i++)
      out_offB[i] = out_off_full[i] + (size_t)b0 * CHs[i] * HW_;
    run_group(embB, emb_allB, Wq, Wmk, Wmv, Wk, Wv, Wm_all, Wp_all,
              out, out_offB, (char*)d_ws, nb, stream);
  }
}

// Round 13
// 751.541 us; speedup vs baseline: 1.0898x; 1.0733x over previous
//
#include <hip/hip_runtime.h>
#include <hip/hip_bf16.h>
#include <math.h>

typedef __hip_bfloat16 bf16;
typedef __attribute__((ext_vector_type(8))) short short8;
typedef __attribute__((ext_vector_type(8))) unsigned short u16x8;
typedef __attribute__((ext_vector_type(4))) float f32x4;
typedef long long ll;

#define B_ 8
#define HEADS_ 4
#define KV_ 960
#define HW_ 1024
#define CKV_ 3840   // KV_*HEADS_

// ---------------------------------------------------------------------------
// helpers
// ---------------------------------------------------------------------------
__device__ __forceinline__ float wredsum(float v) {
#pragma unroll
  for (int o = 32; o > 0; o >>= 1) v += __shfl_xor(v, o);
  return v;
}
__device__ __forceinline__ float wredmax(float v) {
#pragma unroll
  for (int o = 32; o > 0; o >>= 1) v = fmaxf(v, __shfl_xor(v, o));
  return v;
}

__device__ __forceinline__ float bfu2f(unsigned short u) {
  union { unsigned int i; float f; } c;
  c.i = ((unsigned int)u) << 16;
  return c.f;
}
__device__ __forceinline__ unsigned short f2bfu(float f) {
  bf16 h = __float2bfloat16(f);
  return *(unsigned short*)&h;
}

__device__ __forceinline__ void gl_lds16(const void* g, void* l) {
  __builtin_amdgcn_global_load_lds(
      (const __attribute__((address_space(1))) unsigned*)g,
      (__attribute__((address_space(3))) unsigned*)l, 16, 0, 0);
}

// ---------------------------------------------------------------------------
// K0a: elementwise f32 -> bf16 cast (weights). n % 4 == 0.
// ---------------------------------------------------------------------------
__global__ void __launch_bounds__(256) castw(const float* __restrict__ in,
                                             bf16* __restrict__ out, int n) {
  int i = (blockIdx.x * 256 + threadIdx.x) * 4;
  if (i < n) {
    float4 v = *(const float4*)(in + i);
    out[i] = __float2bfloat16(v.x);
    out[i + 1] = __float2bfloat16(v.y);
    out[i + 2] = __float2bfloat16(v.z);
    out[i + 3] = __float2bfloat16(v.w);
  }
}

// ---------------------------------------------------------------------------
// K0b: transpose+cast: in [z][R][1024] f32 -> out [z][1024][R] bf16.
// ---------------------------------------------------------------------------
template <typename InT>
__global__ void __launch_bounds__(256) tcast(const InT* __restrict__ in,
                                             bf16* __restrict__ out, int R,
                                             ll inZ, ll outZ) {
  __shared__ float t[32][33];
  const int x = threadIdx.x & 31, y0 = threadIdx.x >> 5;
  const int c0 = blockIdx.x << 5, r0 = blockIdx.y << 5;
  const InT* ip = in + (ll)blockIdx.z * inZ + (ll)r0 * 1024 + c0;
  bf16* op = out + (ll)blockIdx.z * outZ + (ll)c0 * R + r0;
#pragma unroll
  for (int i = 0; i < 4; i++) {
    int r = y0 + i * 8;
    float v;
    if constexpr (__is_same(InT, float)) v = ip[(ll)r * 1024 + x];
    else v = __bfloat162float(ip[(ll)r * 1024 + x]);
    t[r][x] = v;
  }
  __syncthreads();
#pragma unroll
  for (int i = 0; i < 4; i++) {
    int cc = y0 + i * 8;
    op[(ll)cc * R + x] = __float2bfloat16(t[x][cc]);
  }
}

// ---------------------------------------------------------------------------
// gemm_mfma: 128x128 / BK=32 / 2-phase dbuf (proven).
// OUTMODE 0: f32 [m][n] / 1: bf16 [m][n] / 2: bf16 [n][m]. STATS on 0 and 1.
// ---------------------------------------------------------------------------
template <int OUTMODE, bool STATS>
__global__ void __launch_bounds__(256) gemm_mfma(
    const bf16* __restrict__ A, const bf16* __restrict__ Bt, void* __restrict__ Y,
    int M, int N, int K, int nh,
    ll aZ, ll aH, ll bZ, ll bH, ll yZ, int ldy, float scale,
    float* __restrict__ part) {
  __shared__ bf16 As[2][128 * 32];
  __shared__ bf16 Bs[2][128 * 32];
  __shared__ float rs1[4], rs2[4];
  const int tid = threadIdx.x;
  const int lane = tid & 63;
  const int wave = tid >> 6;
  const int wr = wave >> 1, wc = wave & 1;

  const int gy = gridDim.y, gz = gridDim.z;
  int orig = (blockIdx.z * gy + blockIdx.y) * 8 + blockIdx.x;
  int cpx = (gy * gz);
  int flat = (orig & 7) * cpx + (orig >> 3);
  const int lx = flat & 7;
  int rest = flat >> 3;
  const int ly = rest % gy;
  const int lz = rest / gy;

  const int z = lz;
  const int m0 = ly << 7, n0 = lx << 7;

  f32x4 acc[4][4];
#pragma unroll
  for (int i = 0; i < 4; i++)
#pragma unroll
    for (int j = 0; j < 4; j++) acc[i][j] = (f32x4){0.f, 0.f, 0.f, 0.f};

  const int frow = lane & 15;
  const int kq = lane >> 4;

  const bf16* Ah = A + (ll)z * aZ;
  const bf16* Bh = Bt + (ll)z * bZ;
  int k0n = 0;

  auto stage = [&](int buf) {
#pragma unroll
    for (int t = 0; t < 2; t++) {
      const int e = (wave * 2 + t) * 64 + lane;
      const int row = e >> 2;
      const int ks = (e & 3) ^ ((row >> 1) & 3);
      int gr = m0 + row; gr = gr < M ? gr : M - 1;
      gl_lds16(Ah + (ll)gr * K + k0n + ks * 8,
               (char*)&As[buf][0] + (wave * 2 + t) * 1024);
      int rn = n0 + row; rn = rn < N ? rn : N - 1;
      gl_lds16(Bh + (ll)rn * K + k0n + ks * 8,
               (char*)&Bs[buf][0] + (wave * 2 + t) * 1024);
    }
  };

  const int kpt = K >> 5;
  const int iters = nh * kpt;
  stage(0);
  __syncthreads();

  int buf = 0;
  for (int it = 0; it < iters; ++it) {
    if (it + 1 < iters) {
      k0n += 32;
      if (k0n == K) { k0n = 0; Ah += aH; Bh += bH; }
      stage(buf ^ 1);
    }
    short8 af[4], bfr[4];
#pragma unroll
    for (int fm = 0; fm < 4; fm++) {
      const int row = wr * 64 + fm * 16 + frow;
      af[fm] = *(const short8*)&As[buf][((row << 2) | (kq ^ ((row >> 1) & 3))) << 3];
    }
#pragma unroll
    for (int fn = 0; fn < 4; fn++) {
      const int row = wc * 64 + fn * 16 + frow;
      bfr[fn] = *(const short8*)&Bs[buf][((row << 2) | (kq ^ ((row >> 1) & 3))) << 3];
    }
#pragma unroll
    for (int fm = 0; fm < 4; fm++)
#pragma unroll
      for (int fn = 0; fn < 4; fn++)
        acc[fm][fn] = __builtin_amdgcn_mfma_f32_16x16x32_bf16(
            af[fm], bfr[fn], acc[fm][fn], 0, 0, 0);
    __syncthreads();
    buf ^= 1;
  }

  const int rq = kq << 2;
  float lsum = 0.f, lsq = 0.f;
#pragma unroll
  for (int fm = 0; fm < 4; fm++) {
    const int mrow = m0 + wr * 64 + fm * 16 + rq;
#pragma unroll
    for (int fn = 0; fn < 4; fn++) {
      const int ncol = n0 + wc * 64 + fn * 16 + frow;
      if (ncol >= N) continue;
      if constexpr (OUTMODE == 0) {
        float* Yp = (float*)Y + (ll)z * yZ;
#pragma unroll
        for (int i = 0; i < 4; i++)
          if (mrow + i < M) {
            float v = acc[fm][fn][i] * scale;
            Yp[(ll)(mrow + i) * ldy + ncol] = v;
            if constexpr (STATS) { lsum += v; lsq += v * v; }
          }
      } else if constexpr (OUTMODE == 1) {
        bf16* Yp = (bf16*)Y + (ll)z * yZ;
#pragma unroll
        for (int i = 0; i < 4; i++)
          if (mrow + i < M) {
            float v = acc[fm][fn][i] * scale;
            Yp[(ll)(mrow + i) * ldy + ncol] = __float2bfloat16(v);
            if constexpr (STATS) { lsum += v; lsq += v * v; }
          }
      } else {
        if (mrow < M) {
          bf16* Yp = (bf16*)Y + (ll)z * yZ + (ll)ncol * ldy + mrow;
#pragma unroll
          for (int i = 0; i < 4; i++)
            Yp[i] = __float2bfloat16(acc[fm][fn][i] * scale);
        }
      }
    }
  }
  if constexpr (STATS) {
    lsum = wredsum(lsum);
    lsq = wredsum(lsq);
    if (lane == 0) { rs1[wave] = lsum; rs2[wave] = lsq; }
    __syncthreads();
    if (tid == 0) {
      int slot = ly * 8 + lx;
      part[((ll)z * 32 + slot) * 2] = rs1[0] + rs1[1] + rs1[2] + rs1[3];
      part[((ll)z * 32 + slot) * 2 + 1] = rs2[0] + rs2[1] + rs2[2] + rs2[3];
    }
  }
}

// ---------------------------------------------------------------------------
// gemm8: 256x256, BK=64, 512 thr, dbuf, 4-phase counted-vmcnt (R10-proven,
// R12 front-load). STATS on OUTMODE 0 and 1.
// ---------------------------------------------------------------------------
template <int OUTMODE, bool STATS>
__global__ void __launch_bounds__(512, 2) gemm8(
    const bf16* __restrict__ A, const bf16* __restrict__ Bt, void* __restrict__ Y,
    int M, int N, int K, int nh,
    ll aZ, ll aH, ll bZ, ll bH, ll yZ, int ldy, float scale,
    float* __restrict__ part) {
  __shared__ char lds[131072];           // [A0|A1|B0|B1] each 32KB
  __shared__ float rs1[8], rs2[8];
  const int tid = threadIdx.x;
  const int lane = tid & 63;
  const int wave = tid >> 6;
  const int wm = wave >> 2, wn = wave & 3;

  const int nx = gridDim.x, my = gridDim.y;
  const int nwg = nx * my * gridDim.z;
  int orig = (blockIdx.z * my + blockIdx.y) * nx + blockIdx.x;
  int q8 = nwg >> 3, r8 = nwg & 7;
  int xcd = orig & 7, bidx = orig >> 3;
  int flat = (xcd < r8) ? xcd * (q8 + 1) + bidx
                        : r8 * (q8 + 1) + (xcd - r8) * q8 + bidx;
  const int lx = flat % nx;
  int rest = flat / nx;
  const int ly = rest % my;
  const int lz = rest / my;

  const int m0 = ly << 8, n0 = lx << 8;
  const int ktiles = K >> 6;
  const int nt = nh * ktiles;

  f32x4 acc[8][4];
#pragma unroll
  for (int i = 0; i < 8; i++)
#pragma unroll
    for (int j = 0; j < 4; j++) acc[i][j] = (f32x4){0.f, 0.f, 0.f, 0.f};

  const int frow = lane & 15;
  const int kq = lane >> 4;
  const int swz = frow & 7;

  auto stageRound = [&](int matB, int r, int tt, int buf) {
    int h = tt / ktiles;
    int koff = (tt % ktiles) << 6;
    int s = (r << 9) + tid;
    int row = s >> 3;
    int ks = (s & 7) ^ (row & 7);
    const bf16* src;
    char* dst;
    if (!matB) {
      int gr = m0 + row; gr = gr < M ? gr : M - 1;
      src = A + (ll)lz * aZ + (ll)h * aH + (ll)gr * K + koff + (ks << 3);
      dst = lds + buf * 32768 + (((r << 3) + wave) << 10);
    } else {
      int gr = n0 + row; gr = gr < N ? gr : N - 1;
      src = Bt + (ll)lz * bZ + (ll)h * bH + (ll)gr * K + koff + (ks << 3);
      dst = lds + 65536 + buf * 32768 + (((r << 3) + wave) << 10);
    }
    gl_lds16(src, dst);
  };

  auto readA = [&](int fm, int kh, int cur) -> short8 {
    int row = wm * 128 + fm * 16 + frow;
    int slot = (kq + (kh << 2)) ^ swz;
    return *(const short8*)(lds + cur * 32768 + row * 128 + slot * 16);
  };
  auto readB = [&](int fn, int kh, int cur) -> short8 {
    int row = wn * 64 + fn * 16 + frow;
    int slot = (kq + (kh << 2)) ^ swz;
    return *(const short8*)(lds + 65536 + cur * 32768 + row * 128 + slot * 16);
  };

  stageRound(1, 0, 0, 0); stageRound(1, 1, 0, 0);
  stageRound(1, 2, 0, 0); stageRound(1, 3, 0, 0);
  stageRound(0, 0, 0, 0); stageRound(0, 2, 0, 0);
  stageRound(0, 1, 0, 0); stageRound(0, 3, 0, 0);

  int cur = 0;
  for (int tt = 0; tt < nt; ++tt) {
    const bool hasNext = (tt + 1 < nt);
    short8 bfr[4][2];
#pragma unroll
    for (int p = 0; p < 4; p++) {
      if (p == 0) {
        if (hasNext) asm volatile("s_waitcnt vmcnt(2)" ::: "memory");
        else         asm volatile("s_waitcnt vmcnt(0)" ::: "memory");
        __builtin_amdgcn_s_barrier();
        __builtin_amdgcn_sched_barrier(0);
#pragma unroll
        for (int fn = 0; fn < 4; fn++)
#pragma unroll
          for (int kh = 0; kh < 2; kh++) bfr[fn][kh] = readB(fn, kh, cur);
      }
      if (p == 2) {
        if (hasNext) asm volatile("s_waitcnt vmcnt(6)" ::: "memory");
        __builtin_amdgcn_s_barrier();
        __builtin_amdgcn_sched_barrier(0);
      }
      short8 a0k0 = readA(2 * p, 0, cur), a0k1 = readA(2 * p, 1, cur);
      short8 a1k0 = readA(2 * p + 1, 0, cur), a1k1 = readA(2 * p + 1, 1, cur);
      if (hasNext) {
        if (p == 0) {
          stageRound(1, 0, tt + 1, cur ^ 1); stageRound(1, 1, tt + 1, cur ^ 1);
          stageRound(1, 2, tt + 1, cur ^ 1); stageRound(1, 3, tt + 1, cur ^ 1);
        } else if (p == 1) {
          stageRound(0, 0, tt + 1, cur ^ 1); stageRound(0, 2, tt + 1, cur ^ 1);
        } else if (p == 2) {
          stageRound(0, 1, tt + 1, cur ^ 1); stageRound(0, 3, tt + 1, cur ^ 1);
        }
      }
      __builtin_amdgcn_s_setprio(1);
#pragma unroll
      for (int fn = 0; fn < 4; fn++) {
        acc[2 * p][fn] = __builtin_amdgcn_mfma_f32_16x16x32_bf16(
            a0k0, bfr[fn][0], acc[2 * p][fn], 0, 0, 0);
        acc[2 * p][fn] = __builtin_amdgcn_mfma_f32_16x16x32_bf16(
            a0k1, bfr[fn][1], acc[2 * p][fn], 0, 0, 0);
        acc[2 * p + 1][fn] = __builtin_amdgcn_mfma_f32_16x16x32_bf16(
            a1k0, bfr[fn][0], acc[2 * p + 1][fn], 0, 0, 0);
        acc[2 * p + 1][fn] = __builtin_amdgcn_mfma_f32_16x16x32_bf16(
            a1k1, bfr[fn][1], acc[2 * p + 1][fn], 0, 0, 0);
      }
      __builtin_amdgcn_s_setprio(0);
    }
    cur ^= 1;
  }

  const int rq = kq << 2;
  float lsum = 0.f, lsq = 0.f;
#pragma unroll
  for (int fm = 0; fm < 8; fm++) {
    const int mrow = m0 + wm * 128 + fm * 16 + rq;
#pragma unroll
    for (int fn = 0; fn < 4; fn++) {
      const int ncol = n0 + wn * 64 + fn * 16 + frow;
      if (ncol >= N) continue;
      if constexpr (OUTMODE == 0) {
        float* Yp = (float*)Y + (ll)lz * yZ;
#pragma unroll
        for (int i = 0; i < 4; i++)
          if (mrow + i < M) {
            float v = acc[fm][fn][i] * scale;
            Yp[(ll)(mrow + i) * ldy + ncol] = v;
            if constexpr (STATS) { lsum += v; lsq += v * v; }
          }
      } else if constexpr (OUTMODE == 1) {
        bf16* Yp = (bf16*)Y + (ll)lz * yZ;
#pragma unroll
        for (int i = 0; i < 4; i++)
          if (mrow + i < M) {
            float v = acc[fm][fn][i] * scale;
            Yp[(ll)(mrow + i) * ldy + ncol] = __float2bfloat16(v);
            if constexpr (STATS) { lsum += v; lsq += v * v; }
          }
      } else {
        if (mrow < M) {
          bf16* Yp = (bf16*)Y + (ll)lz * yZ + (ll)ncol * ldy + mrow;
#pragma unroll
          for (int i = 0; i < 4; i++)
            Yp[i] = __float2bfloat16(acc[fm][fn][i] * scale);
        }
      }
    }
  }
  if constexpr (STATS) {
    lsum = wredsum(lsum);
    lsq = wredsum(lsq);
    if (lane == 0) { rs1[wave] = lsum; rs2[wave] = lsq; }
    __syncthreads();
    if (tid == 0) {
      float s = 0.f, s2 = 0.f;
#pragma unroll
      for (int w = 0; w < 8; w++) { s += rs1[w]; s2 += rs2[w]; }
      int slot = ly * nx + lx;
      part[((ll)lz * 32 + slot) * 2] = s;
      part[((ll)lz * 32 + slot) * 2 + 1] = s2;
    }
  }
}

// ---------------------------------------------------------------------------
// pv_reduce: OtT[b][off] = 0.25 * sum_{s<4} part[(b*4+s)][off]  (bf16)
// ---------------------------------------------------------------------------
__global__ void __launch_bounds__(256) pv_reduce(const bf16* __restrict__ part,
                                                 bf16* __restrict__ out,
                                                 int planeShift) {
  const ll idx = ((ll)blockIdx.x * 256 + threadIdx.x) * 4;
  const int b = (int)(idx >> planeShift);
  const ll off = idx - ((ll)b << planeShift);
  const bf16* base = part + (((ll)b * 4) << planeShift) + off;
  float a0 = 0.f, a1 = 0.f, a2 = 0.f, a3 = 0.f;
#pragma unroll
  for (int s = 0; s < 4; s++) {
    ushort4 u = *(const ushort4*)(base + ((ll)s << planeShift));
    a0 += bfu2f(u.x); a1 += bfu2f(u.y); a2 += bfu2f(u.z); a3 += bfu2f(u.w);
  }
  ushort4 o;
  o.x = f2bfu(a0 * 0.25f);
  o.y = f2bfu(a1 * 0.25f);
  o.z = f2bfu(a2 * 0.25f);
  o.w = f2bfu(a3 * 0.25f);
  *(ushort4*)(out + idx) = o;
}

// ---------------------------------------------------------------------------
// K2: depthwise 3x3 (pad 1), optional fused l2norm. 256 thr, 4 px/thread.
// ---------------------------------------------------------------------------
template <bool NORM>
__global__ void __launch_bounds__(256) dw3x3v(const bf16* __restrict__ in,
                                              const float* __restrict__ w9,
                                              bf16* __restrict__ out, int C) {
  __shared__ float tile[34][36];
  __shared__ float red[4];
  const int bc = blockIdx.x;
  const int ch = bc % C;
  const int tid = threadIdx.x;
  const int y = tid >> 3;
  const int x0 = (tid & 7) << 2;
  const bf16* ip = in + ((size_t)bc << 10);

  ushort4 u = *(const ushort4*)(ip + (y << 5) + x0);
  tile[y + 1][x0 + 1] = bfu2f(u.x);
  tile[y + 1][x0 + 2] = bfu2f(u.y);
  tile[y + 1][x0 + 3] = bfu2f(u.z);
  tile[y + 1][x0 + 4] = bfu2f(u.w);
  if (tid < 34) { tile[0][tid] = 0.f; tile[33][tid] = 0.f; }
  if (tid < 32) { tile[tid + 1][0] = 0.f; tile[tid + 1][33] = 0.f; }
  __syncthreads();

  const float* wc = w9 + ch * 9;
  float s[4] = {0.f, 0.f, 0.f, 0.f};
#pragma unroll
  for (int dy = 0; dy < 3; dy++) {
    const float* tr = &tile[y + dy][x0];
    float c0 = tr[0], c1 = tr[1], c2 = tr[2], c3 = tr[3], c4 = tr[4], c5 = tr[5];
    float wa = wc[dy * 3], wb = wc[dy * 3 + 1], wd = wc[dy * 3 + 2];
    s[0] += c0 * wa + c1 * wb + c2 * wd;
    s[1] += c1 * wa + c2 * wb + c3 * wd;
    s[2] += c2 * wa + c3 * wb + c4 * wd;
    s[3] += c3 * wa + c4 * wb + c5 * wd;
  }

  float inv = 1.f;
  if (NORM) {
    float ss = s[0] * s[0] + s[1] * s[1] + s[2] * s[2] + s[3] * s[3];
    ss = wredsum(ss);
    const int lane = tid & 63, wid = tid >> 6;
    if (lane == 0) red[wid] = ss;
    __syncthreads();
    inv = 1.0f / fmaxf(sqrtf(red[0] + red[1] + red[2] + red[3]), 1e-12f);
  }
  ushort4 o4;
  o4.x = f2bfu(s[0] * inv);
  o4.y = f2bfu(s[1] * inv);
  o4.z = f2bfu(s[2] * inv);
  o4.w = f2bfu(s[3] * inv);
  *(ushort4*)(out + ((size_t)bc << 10) + (y << 5) + x0) = o4;
}

// ---------------------------------------------------------------------------
// dwtcast: V path fused depthwise-3x3 + transpose. One pass.
// ---------------------------------------------------------------------------
__global__ void __launch_bounds__(256) dwtcast(const bf16* __restrict__ in,
                                               const float* __restrict__ w9,
                                               bf16* __restrict__ out) {
  __shared__ float t[3][32][34];
  const int jt = blockIdx.x;
  const int y = blockIdx.y;
  const int bh = blockIdx.z;
  const int b = bh >> 2, h = bh & 3;
  const int j0 = jt << 5;
  const int tid = threadIdx.x;

  if (tid < 192) {
    const int rr = tid / 64;
    const int rem = tid - rr * 64;
    const int jc = rem >> 1;
    const int half = rem & 1;
    const int iy = y - 1 + rr;
    float* dstp = &t[rr][jc][1 + (half << 4)];
    if (iy < 0 || iy > 31) {
#pragma unroll
      for (int u = 0; u < 16; u++) dstp[u] = 0.f;
    } else {
      const bf16* src = in + (((ll)b * CKV_ + h * KV_ + j0 + jc) << 10) +
                        (iy << 5) + (half << 4);
      u16x8 v0 = *(const u16x8*)src;
      u16x8 v1 = *(const u16x8*)(src + 8);
#pragma unroll
      for (int u = 0; u < 8; u++) dstp[u] = bfu2f(v0[u]);
#pragma unroll
      for (int u = 0; u < 8; u++) dstp[8 + u] = bfu2f(v1[u]);
    }
  }
  if (tid < 96) {
    const int rr = tid / 32, jc = tid - rr * 32;
    t[rr][jc][0] = 0.f;
    t[rr][jc][33] = 0.f;
  }
  __syncthreads();

  const int jp = tid & 15;
  const int xq = tid >> 4;
  const int ch0 = jp << 1;
  const float* wA = w9 + ((size_t)h * KV_ + j0 + ch0) * 9;
  const float* wB = wA + 9;

  bf16* orow = out + (ll)bh * 983040 + (ll)j0 + (ch0);
#pragma unroll
  for (int sx = 0; sx < 2; sx++) {
    const int x = xq + (sx << 4);
    float sA = 0.f, sB = 0.f;
#pragma unroll
    for (int dy = 0; dy < 3; dy++) {
      const float* rA = &t[dy][ch0][x];
      const float* rB = &t[dy][ch0 + 1][x];
      sA += rA[0] * wA[dy * 3] + rA[1] * wA[dy * 3 + 1] + rA[2] * wA[dy * 3 + 2];
      sB += rB[0] * wB[dy * 3] + rB[1] * wB[dy * 3 + 1] + rB[2] * wB[dy * 3 + 2];
    }
    const int n = (y << 5) + x;
    ushort2 o;
    o.x = f2bfu(sA);
    o.y = f2bfu(sB);
    *(ushort2*)(orow + (ll)n * 960) = o;
  }
}

// ---------------------------------------------------------------------------
// K3: paired grouped 3x3 + l2norm. One block computes BOTH outputs (2g, 2g+1)
// that share input planes (2g, 2g+1) -> input read once (was twice).
// grid: nb * C4/2 blocks; 256 thr, 4 px/thread per output.
// ---------------------------------------------------------------------------
__global__ void __launch_bounds__(256) gq3x3v2(const bf16* __restrict__ in,
                                               const float* __restrict__ wq,
                                               bf16* __restrict__ out, int C4) {
  __shared__ float t0[34][36];
  __shared__ float t1[34][36];
  __shared__ float red[8];
  const int G = C4 >> 1;
  const int bo = blockIdx.x;
  const int g = bo % G;
  const int b = bo / G;
  const int ic0 = g << 1;
  const int tid = threadIdx.x;
  const int y = tid >> 3;
  const int x0 = (tid & 7) << 2;
  const bf16* p0 = in + (((size_t)b * C4 + ic0) << 10);

  ushort4 u0 = *(const ushort4*)(p0 + (y << 5) + x0);
  ushort4 u1 = *(const ushort4*)(p0 + 1024 + (y << 5) + x0);
  t0[y + 1][x0 + 1] = bfu2f(u0.x);
  t0[y + 1][x0 + 2] = bfu2f(u0.y);
  t0[y + 1][x0 + 3] = bfu2f(u0.z);
  t0[y + 1][x0 + 4] = bfu2f(u0.w);
  t1[y + 1][x0 + 1] = bfu2f(u1.x);
  t1[y + 1][x0 + 2] = bfu2f(u1.y);
  t1[y + 1][x0 + 3] = bfu2f(u1.z);
  t1[y + 1][x0 + 4] = bfu2f(u1.w);
  if (tid < 34) {
    t0[0][tid] = 0.f; t0[33][tid] = 0.f;
    t1[0][tid] = 0.f; t1[33][tid] = 0.f;
  }
  if (tid < 32) {
    t0[tid + 1][0] = 0.f; t0[tid + 1][33] = 0.f;
    t1[tid + 1][0] = 0.f; t1[tid + 1][33] = 0.f;
  }
  __syncthreads();

  const float* wA = wq + (size_t)(ic0) * 18;      // output 2g
  const float* wB = wq + (size_t)(ic0 + 1) * 18;  // output 2g+1
  float sA[4] = {0.f, 0.f, 0.f, 0.f};
  float sB[4] = {0.f, 0.f, 0.f, 0.f};
#pragma unroll
  for (int dy = 0; dy < 3; dy++) {
    const float* r0 = &t0[y + dy][x0];
    const float* r1 = &t1[y + dy][x0];
    float c0 = r0[0], c1 = r0[1], c2 = r0[2], c3 = r0[3], c4 = r0[4], c5 = r0[5];
    float d0 = r1[0], d1 = r1[1], d2 = r1[2], d3 = r1[3], d4 = r1[4], d5 = r1[5];
    {
      float wa = wA[dy * 3], wb = wA[dy * 3 + 1], wd = wA[dy * 3 + 2];
      float va = wA[9 + dy * 3], vb = wA[9 + dy * 3 + 1], vd = wA[9 + dy * 3 + 2];
      sA[0] += c0 * wa + c1 * wb + c2 * wd + d0 * va + d1 * vb + d2 * vd;
      sA[1] += c1 * wa + c2 * wb + c3 * wd + d1 * va + d2 * vb + d3 * vd;
      sA[2] += c2 * wa + c3 * wb + c4 * wd + d2 * va + d3 * vb + d4 * vd;
      sA[3] += c3 * wa + c4 * wb + c5 * wd + d3 * va + d4 * vb + d5 * vd;
    }
    {
      float wa = wB[dy * 3], wb = wB[dy * 3 + 1], wd = wB[dy * 3 + 2];
      float va = wB[9 + dy * 3], vb = wB[9 + dy * 3 + 1], vd = wB[9 + dy * 3 + 2];
      sB[0] += c0 * wa + c1 * wb + c2 * wd + d0 * va + d1 * vb + d2 * vd;
      sB[1] += c1 * wa + c2 * wb + c3 * wd + d1 * va + d2 * vb + d3 * vd;
      sB[2] += c2 * wa + c3 * wb + c4 * wd + d2 * va + d3 * vb + d4 * vd;
      sB[3] += c3 * wa + c4 * wb + c5 * wd + d3 * va + d4 * vb + d5 * vd;
    }
  }

  float ssA = sA[0] * sA[0] + sA[1] * sA[1] + sA[2] * sA[2] + sA[3] * sA[3];
  float ssB = sB[0] * sB[0] + sB[1] * sB[1] + sB[2] * sB[2] + sB[3] * sB[3];
  ssA = wredsum(ssA);
  ssB = wredsum(ssB);
  const int lane = tid & 63, wid = tid >> 6;
  if (lane == 0) { red[wid * 2] = ssA; red[wid * 2 + 1] = ssB; }
  __syncthreads();
  float invA = 1.0f / fmaxf(sqrtf(red[0] + red[2] + red[4] + red[6]), 1e-12f);
  float invB = 1.0f / fmaxf(sqrtf(red[1] + red[3] + red[5] + red[7]), 1e-12f);

  bf16* opA = out + (((size_t)b * C4 + ic0) << 10) + (y << 5) + x0;
  ushort4 oA;
  oA.x = f2bfu(sA[0] * invA);
  oA.y = f2bfu(sA[1] * invA);
  oA.z = f2bfu(sA[2] * invA);
  oA.w = f2bfu(sA[3] * invA);
  *(ushort4*)opA = oA;
  ushort4 oB;
  oB.x = f2bfu(sB[0] * invB);
  oB.y = f2bfu(sB[1] * invB);
  oB.z = f2bfu(sB[2] * invB);
  oB.w = f2bfu(sB[3] * invB);
  *(ushort4*)(opA + 1024) = oB;
}

// ---------------------------------------------------------------------------
// K6: row softmax over 960 (bf16 in/out) with inline InstanceNorm stats.
// thread t handles 4 contiguous cols j0 = 4t (vector ushort4 load/store).
// ---------------------------------------------------------------------------
__global__ void __launch_bounds__(256) softmax_rows(const bf16* __restrict__ attn,
                                                    const float* __restrict__ part,
                                                    int nslots,
                                                    bf16* __restrict__ probs, int c) {
  __shared__ float rm[4], rs[4];
  const int row = blockIdx.x;
  const int bh = row / c;
  const bf16* p = attn + (size_t)row * 960;
  bf16* op = probs + (size_t)row * 960;
  const int tid = threadIdx.x;
  const int j0 = tid << 2;
  const bool act = (j0 < 960);

  float s = 0.f, s2 = 0.f;
  for (int i = 0; i < nslots; i++) {
    s += part[((ll)bh * 32 + i) * 2];
    s2 += part[((ll)bh * 32 + i) * 2 + 1];
  }
  const float n = (float)(c * 960);
  const float mu = s / n;
  const float var = s2 / n - mu * mu;
  const float rstd = rsqrtf(var + 1e-5f);

  float v[4];
  float mx = -1e30f;
  if (act) {
    ushort4 u = *(const ushort4*)(p + j0);
    v[0] = (bfu2f(u.x) - mu) * rstd;
    v[1] = (bfu2f(u.y) - mu) * rstd;
    v[2] = (bfu2f(u.z) - mu) * rstd;
    v[3] = (bfu2f(u.w) - mu) * rstd;
    mx = fmaxf(fmaxf(v[0], v[1]), fmaxf(v[2], v[3]));
  }
  mx = wredmax(mx);
  const int lane = tid & 63, wid = tid >> 6;
  if (lane == 0) rm[wid] = mx;
  __syncthreads();
  mx = fmaxf(fmaxf(rm[0], rm[1]), fmaxf(rm[2], rm[3]));

  float sum = 0.f;
  if (act) {
#pragma unroll
    for (int u = 0; u < 4; u++) {
      v[u] = __expf(v[u] - mx);
      sum += v[u];
    }
  }
  sum = wredsum(sum);
  if (lane == 0) rs[wid] = sum;
  __syncthreads();
  sum = rs[0] + rs[1] + rs[2] + rs[3];
  const float inv = 1.0f / sum;
  if (act) {
    ushort4 o;
    o.x = f2bfu(v[0] * inv);
    o.y = f2bfu(v[1] * inv);
    o.z = f2bfu(v[2] * inv);
    o.w = f2bfu(v[3] * inv);
    *(ushort4*)(op + j0) = o;
  }
}

// ---------------------------------------------------------------------------
// Workspace plan — identical to R6..R12 (proven to fit); attnb now bf16.
// ---------------------------------------------------------------------------
static size_t p4_size(int nb) {
  const int chunkB = (nb + 1) / 2;
  size_t a = (size_t)nb * 4194304;
  size_t b = (size_t)nb * 1966080 + 7372800;
  size_t c = (size_t)chunkB * 7864320;
  size_t m = a > b ? a : b;
  return m > c ? m : c;
}
static size_t p5_size(int nb) {
  size_t a = (size_t)nb * 1048576;
  return a > 7372800 ? a : 7372800;
}
static size_t total_need(int nb) {
  return 3 * (size_t)nb * 7864320 + p4_size(nb) + p5_size(nb) + 3490816;
}

static void run_group(const float* const emb[4], const float* emb_all,
                      const float* const Wq[4],
                      const float* Wmk, const float* Wmv,
                      const float* Wk, const float* Wv,
                      bf16* Wm_all, bf16* Wp_all,
                      float* out, const size_t* out_off,
                      char* ws, int nb, hipStream_t stream) {
  const size_t szBig = (size_t)nb * 7864320;
  char* P1 = ws;
  char* P2 = P1 + szBig;
  char* P3 = P2 + szBig;
  char* P4 = P3 + szBig;
  char* P5 = P4 + p4_size(nb);
  char* FX = P5 + p5_size(nb);

  bf16* kbuf = (bf16*)P1;
  bf16* vt   = (bf16*)P2;
  bf16* kvexp = (bf16*)P3;
  bf16* attnb = (bf16*)P3;    // QK output, bf16 (R13)
  bf16* pvpart = (bf16*)P3;
  bf16* embT_all = (bf16*)P4;
  bf16* Wmv_bf = (bf16*)(P4 + (size_t)nb * 1966080);
  bf16* qbuf = (bf16*)P4;
  bf16* probsb = (bf16*)P4;
  bf16* Wmk_bf = (bf16*)P5;
  bf16* OtT = (bf16*)P5;
  float* part = (float*)(FX + 3482112);

  const float qk_scale = 1.0f / sqrtf((float)KV_);
  const int CHs[4] = {64, 128, 256, 512};
  const size_t wm_off[4] = {0, 16384, 81920, 344064};
  const size_t wp_off[4] = {0, 4096, 20480, 86016};

  // -- prologue: shared K/V --------------------------------------------------
  castw<<<3600, 256, 0, stream>>>(Wmk, Wmk_bf, 3686400);
  castw<<<3600, 256, 0, stream>>>(Wmv, Wmv_bf, 3686400);
  tcast<float><<<dim3(32, 30, nb), 256, 0, stream>>>(emb_all, embT_all, 960,
                                                     983040LL, 983040LL);
  gemm8<1, false><<<dim3(4, 15, nb), 512, 0, stream>>>(
      Wmk_bf, embT_all, kvexp, 3840, 1024, 960, 1, 0, 0, 983040LL, 0,
      3932160LL, 1024, 1.f, nullptr);
  dw3x3v<true><<<nb * CKV_, 256, 0, stream>>>(kvexp, Wk, kbuf, CKV_);
  gemm8<1, false><<<dim3(4, 15, nb), 512, 0, stream>>>(
      Wmv_bf, embT_all, kvexp, 3840, 1024, 960, 1, 0, 0, 983040LL, 0,
      3932160LL, 1024, 1.f, nullptr);
  dwtcast<<<dim3(30, 32, nb * 4), 256, 0, stream>>>(kvexp, Wv, vt);

  // -- branches --------------------------------------------------------------
  for (int br = 0; br < 4; br++) {
    const int c = CHs[br];
    const int C4 = c * 4;
    const int mtiles = (c + 127) / 128;
    bf16* Wm_bf = Wm_all + wm_off[br];
    bf16* Wp_bf = Wp_all + wp_off[br];
    int planeShift = 10;
    for (int t = c; t > 1; t >>= 1) planeShift++;

    tcast<float><<<dim3(32, c / 32, nb), 256, 0, stream>>>(
        emb[br], qbuf, c, (ll)c * 1024, (ll)c * 1024);
    if (c == 512) {
      gemm8<1, false><<<dim3(4, C4 / 256, nb), 512, 0, stream>>>(
          Wm_bf, qbuf, kvexp, C4, 1024, c, 1, 0, 0, (ll)c * 1024, 0,
          (ll)C4 * 1024, 1024, 1.f, nullptr);
    } else {
      gemm_mfma<1, false><<<dim3(8, C4 / 128, nb), 256, 0, stream>>>(
          Wm_bf, qbuf, kvexp, C4, 1024, c, 1, 0, 0, (ll)c * 1024, 0,
          (ll)C4 * 1024, 1024, 1.f, nullptr);
    }
    gq3x3v2<<<nb * (C4 / 2), 256, 0, stream>>>(kvexp, Wq[br], qbuf, C4);
    int nslots;
    if (c == 512) {
      gemm8<1, true><<<dim3(4, c / 256, nb * 4), 512, 0, stream>>>(
          qbuf, kbuf, attnb, c, 960, 1024, 1, (ll)c * 1024, 0, 983040LL, 0,
          (ll)c * 960, 960, qk_scale, part);
      nslots = (c / 256) * 4;
    } else {
      gemm_mfma<1, true><<<dim3(8, mtiles, nb * 4), 256, 0, stream>>>(
          qbuf, kbuf, attnb, c, 960, 1024, 1, (ll)c * 1024, 0, 983040LL, 0,
          (ll)c * 960, 960, qk_scale, part);
      nslots = mtiles * 8;
    }
    softmax_rows<<<nb * 4 * c, 256, 0, stream>>>(attnb, part, nslots, probsb, c);
    if (c == 512) {
      gemm8<2, false><<<dim3(4, c / 256, nb * 4), 512, 0, stream>>>(
          probsb, vt, pvpart, c, 1024, 960, 1, (ll)c * 960, 0, 983040LL, 0,
          (ll)1024 * c, c, 1.f, nullptr);
    } else {
      gemm_mfma<2, false><<<dim3(8, mtiles, nb * 4), 256, 0, stream>>>(
          probsb, vt, pvpart, c, 1024, 960, 1, (ll)c * 960, 0, 983040LL, 0,
          (ll)1024 * c, c, 1.f, nullptr);
    }
    pv_reduce<<<nb * c, 256, 0, stream>>>(pvpart, OtT, planeShift);
    gemm_mfma<0, false><<<dim3(8, mtiles, nb), 256, 0, stream>>>(
        Wp_bf, OtT, out + out_off[br], c, 1024, c, 1, 0, 0,
        (ll)1024 * c, 0, (ll)c * 1024, 1024, 1.f, nullptr);
  }
}

extern "C" void kernel_launch(void* const* d_in, const int* in_sizes, int n_in,
                              void* d_out, int out_size, void* d_ws, size_t ws_size,
                              hipStream_t stream) {
  const float* emb[4] = {(const float*)d_in[0], (const float*)d_in[1],
                         (const float*)d_in[2], (const float*)d_in[3]};
  const float* emb_all = (const float*)d_in[4];
  const float* Wm[4] = {(const float*)d_in[5], (const float*)d_in[8],
                        (const float*)d_in[11], (const float*)d_in[14]};
  const float* Wq[4] = {(const float*)d_in[6], (const float*)d_in[9],
                        (const float*)d_in[12], (const float*)d_in[15]};
  const float* Wp[4] = {(const float*)d_in[7], (const float*)d_in[10],
                        (const float*)d_in[13], (const float*)d_in[16]};
  const float* Wmk = (const float*)d_in[17];
  const float* Wmv = (const float*)d_in[18];
  const float* Wk = (const float*)d_in[19];
  const float* Wv = (const float*)d_in[20];
  float* out = (float*)d_out;

  const int CHs[4] = {64, 128, 256, 512};
  const size_t out_off_full[4] = {0, 524288, 1572864, 3670016};
  const size_t wm_off[4] = {0, 16384, 81920, 344064};
  const size_t wp_off[4] = {0, 4096, 20480, 86016};

  int nb = 1;
  if (ws_size >= total_need(8)) nb = 8;
  else if (ws_size >= total_need(4)) nb = 4;
  else if (ws_size >= total_need(2)) nb = 2;

  char* FX = (char*)d_ws + 3 * (size_t)nb * 7864320 + p4_size(nb) + p5_size(nb);
  bf16* Wm_all = (bf16*)FX;
  bf16* Wp_all = (bf16*)(FX + 2785280);

  for (int br = 0; br < 4; br++) {
    const int c = CHs[br];
    castw<<<(4 * c * c / 4 + 255) / 256, 256, 0, stream>>>(
        Wm[br], Wm_all + wm_off[br], 4 * c * c);
    castw<<<(c * c / 4 + 255) / 256, 256, 0, stream>>>(
        Wp[br], Wp_all + wp_off[br], c * c);
  }

  for (int b0 = 0; b0 < B_; b0 += nb) {
    const float* embB[4];
    for (int i = 0; i < 4; i++) embB[i] = emb[i] + (size_t)b0 * CHs[i] * HW_;
    const float* emb_allB = emb_all + (size_t)b0 * KV_ * HW_;
    size_t out_offB[4];
    for (int i = 0; i < 4; i++)
      out_offB[i] = out_off_full[i] + (size_t)b0 * CHs[i] * HW_;
    run_group(embB, emb_allB, Wq, Wmk, Wmv, Wk, Wv, Wm_all, Wp_all,
              out, out_offB, (char*)d_ws, nb, stream);
  }
}